// Round 1
// baseline (498.371 us; speedup 1.0000x reference)
//
#include <hip/hip_runtime.h>
#include <math.h>

#define SS 2048

typedef __attribute__((ext_vector_type(8))) short s16x8;
typedef __attribute__((ext_vector_type(4))) float f32x4;

__device__ __forceinline__ unsigned short f2bf(float f) {
  union { float f; unsigned u; } a; a.f = f;
  unsigned r = a.u + 0x7fffu + ((a.u >> 16) & 1u);   // RNE
  return (unsigned short)(r >> 16);
}
__device__ __forceinline__ float bf2f(unsigned short b) {
  union { unsigned u; float f; } a; a.u = ((unsigned)b) << 16;
  return a.f;
}
__device__ __forceinline__ void async16(void* lds, const void* g) {
  __builtin_amdgcn_global_load_lds(
      (const __attribute__((address_space(1))) unsigned int*)g,
      (__attribute__((address_space(3))) unsigned int*)lds, 16, 0, 0);
}
__device__ __forceinline__ f32x4 mfma_bf16(s16x8 a, s16x8 b, f32x4 c) {
  return __builtin_amdgcn_mfma_f32_16x16x32_bf16(a, b, c, 0, 0, 0);
}

// ---------- transpose + fp32->bf16: WT[n][k] = bf16(W[k][n]) ----------
__global__ __launch_bounds__(256) void k_transpose(const float* __restrict__ W,
                                                   unsigned short* __restrict__ WT,
                                                   int K, int N) {
  __shared__ float tile[32][33];
  int t = threadIdx.x;
  int tx = t & 31, ty = t >> 5;
  int n0 = blockIdx.x * 32, k0 = blockIdx.y * 32;
#pragma unroll
  for (int i = 0; i < 4; ++i)
    tile[ty + 8 * i][tx] = W[(size_t)(k0 + ty + 8 * i) * N + n0 + tx];
  __syncthreads();
#pragma unroll
  for (int i = 0; i < 4; ++i)
    WT[(size_t)(n0 + ty + 8 * i) * K + k0 + tx] = f2bf(tile[tx][ty + 8 * i]);
}

// ---------- RoPE tables (double precision, once per launch) ----------
__global__ void k_rope_tables(float* __restrict__ cosT, float* __restrict__ sinT) {
  int idx = blockIdx.x * 256 + threadIdx.x;  // 65536 = 2048*32
  int s = idx >> 5, i = idx & 31;
  double ang = (double)s * pow(10000.0, -(double)(2 * i) / 64.0);
  cosT[idx] = (float)cos(ang);
  sinT[idx] = (float)sin(ang);
}

// ---------- RMSNorm fp32 -> bf16 (one block per row, H=1024) ----------
__global__ __launch_bounds__(256) void k_rmsnorm(const float* __restrict__ X,
                                                 const float* __restrict__ Wt,
                                                 unsigned short* __restrict__ Y) {
  int row = blockIdx.x, t = threadIdx.x;
  float4 v = ((const float4*)X)[(size_t)row * 256 + t];
  float ssq = v.x * v.x + v.y * v.y + v.z * v.z + v.w * v.w;
#pragma unroll
  for (int m = 1; m < 64; m <<= 1) ssq += __shfl_xor(ssq, m);
  __shared__ float red[4];
  if ((t & 63) == 0) red[t >> 6] = ssq;
  __syncthreads();
  float sc = rsqrtf((red[0] + red[1] + red[2] + red[3]) * (1.0f / 1024.0f) + 1e-6f);
  float4 wv = ((const float4*)Wt)[t];
  ushort4 o;
  o.x = f2bf(v.x * sc * wv.x); o.y = f2bf(v.y * sc * wv.y);
  o.z = f2bf(v.z * sc * wv.z); o.w = f2bf(v.w * sc * wv.w);
  ((ushort4*)Y)[(size_t)row * 256 + t] = o;
}

// ---------- RoPE apply in place on bf16 [tok][stride], heads of 64 ----------
__global__ __launch_bounds__(256) void k_rope(unsigned short* __restrict__ X,
                                              const float* __restrict__ cosT,
                                              const float* __restrict__ sinT,
                                              int hshift, int stride) {
  int idx = blockIdx.x * 256 + threadIdx.x;
  int seg = idx & 7;
  int h = (idx >> 3) & ((1 << hshift) - 1);
  int tok = idx >> (3 + hshift);
  int s = tok & (SS - 1);
  int d0 = seg * 4;
  unsigned short* p = X + (size_t)tok * stride + h * 64;
  ushort4 lo = *(ushort4*)&p[d0];
  ushort4 hi = *(ushort4*)&p[d0 + 32];
  float4 cs = *(const float4*)&cosT[s * 32 + d0];
  float4 sn = *(const float4*)&sinT[s * 32 + d0];
  ushort4 olo, ohi;
  olo.x = f2bf(bf2f(lo.x) * cs.x - bf2f(hi.x) * sn.x);
  olo.y = f2bf(bf2f(lo.y) * cs.y - bf2f(hi.y) * sn.y);
  olo.z = f2bf(bf2f(lo.z) * cs.z - bf2f(hi.z) * sn.z);
  olo.w = f2bf(bf2f(lo.w) * cs.w - bf2f(hi.w) * sn.w);
  ohi.x = f2bf(bf2f(hi.x) * cs.x + bf2f(lo.x) * sn.x);
  ohi.y = f2bf(bf2f(hi.y) * cs.y + bf2f(lo.y) * sn.y);
  ohi.z = f2bf(bf2f(hi.z) * cs.z + bf2f(lo.z) * sn.z);
  ohi.w = f2bf(bf2f(hi.w) * cs.w + bf2f(lo.w) * sn.w);
  *(ushort4*)&p[d0] = olo;
  *(ushort4*)&p[d0 + 32] = ohi;
}

// ---------- GEMM: C[M,N] = A[M,K](bf16) x BT[N,K](bf16), m97 structure ----------
// EPI: 0 = bf16 store, 1 = fp32 store + fp32 residual, 2 = silu->bf16, 3 = bf16 *Gmul
template <int EPI>
__global__ __launch_bounds__(256) void k_gemm(const unsigned short* __restrict__ A,
                                              const unsigned short* __restrict__ BT,
                                              int N, int K,
                                              unsigned short* Cb,
                                              float* __restrict__ Cf,
                                              const float* __restrict__ Res,
                                              const unsigned short* Gmul) {
  __shared__ __align__(16) unsigned short at[128 * 32];
  __shared__ __align__(16) unsigned short bt[128 * 32];
  int t = threadIdx.x, w = t >> 6, l = t & 63;
  int g = l >> 4, c = l & 15;
  int wm = w >> 1, wn = w & 1;
  f32x4 acc[4][4] = {};
  const unsigned short* gA = A + (size_t)(blockIdx.y * 128 + (t >> 2)) * K + (t & 3) * 8;
  const unsigned short* gB = BT + (size_t)(blockIdx.x * 128 + (t >> 2)) * K + (t & 3) * 8;
  unsigned short* dA = &at[w * 512];  // wave-uniform LDS base; HW adds lane*16B
  unsigned short* dB = &bt[w * 512];
  const int nk = K >> 5;
  for (int kt = 0; kt < nk; ++kt) {
    async16(dA, gA);
    async16(dA + 2048, gA + (size_t)64 * K);
    async16(dB, gB);
    async16(dB + 2048, gB + (size_t)64 * K);
    gA += 32; gB += 32;
    __syncthreads();  // drains vmcnt -> staged tile visible to all waves
    s16x8 af[4], bfr[4];
#pragma unroll
    for (int m = 0; m < 4; ++m) af[m] = *(const s16x8*)&at[(wm * 64 + m * 16 + c) * 32 + g * 8];
#pragma unroll
    for (int n = 0; n < 4; ++n) bfr[n] = *(const s16x8*)&bt[(wn * 64 + n * 16 + c) * 32 + g * 8];
#pragma unroll
    for (int m = 0; m < 4; ++m)
#pragma unroll
      for (int n = 0; n < 4; ++n)
        acc[m][n] = mfma_bf16(af[m], bfr[n], acc[m][n]);
    __syncthreads();  // all reads done before next stage overwrites
  }
  size_t rb = (size_t)blockIdx.y * 128 + wm * 64;
  size_t cbase = (size_t)blockIdx.x * 128 + wn * 64;
#pragma unroll
  for (int m = 0; m < 4; ++m)
#pragma unroll
    for (int n = 0; n < 4; ++n)
#pragma unroll
      for (int r = 0; r < 4; ++r) {
        size_t row = rb + m * 16 + g * 4 + r;      // C row = (lane>>4)*4+reg
        size_t col = cbase + n * 16 + c;           // C col = lane&15
        float v = acc[m][n][r];
        if (EPI == 0) Cb[row * N + col] = f2bf(v);
        else if (EPI == 1) Cf[row * N + col] = v + Res[row * N + col];
        else if (EPI == 2) Cb[row * N + col] = f2bf(v / (1.0f + __expf(-v)));
        else Cb[row * N + col] = f2bf(bf2f(Gmul[row * N + col]) * v);
      }
}

// ---------- Flash attention, GQA: block=(b,kvh,64 q rows), 16 waves ----------
// wave w: q-head kvh*4+(w&3), q rows (w>>2)*16 .. +16.  K/VT/mask LDS shared.
__global__ __launch_bounds__(1024) void k_attn(const unsigned short* __restrict__ Q,
                                               const unsigned short* __restrict__ KV,
                                               const float* __restrict__ mask,
                                               unsigned short* __restrict__ Out) {
  __shared__ __align__(16) unsigned short Ks[64 * 72];
  __shared__ __align__(16) unsigned short VTs[64 * 72];
  __shared__ __align__(16) unsigned short Ms[64 * 72];
  __shared__ __align__(16) unsigned short Ps[16 * 16 * 72];
  int t = threadIdx.x, w = t >> 6, l = t & 63;
  int g = l >> 4, c = l & 15;
  int qw = w >> 2, hh = w & 3;
  int blk = blockIdx.x;
  int b = blk >> 7, kvh = (blk >> 5) & 3, qt = blk & 31;
  size_t tokQ = (size_t)b * SS + qt * 64 + qw * 16;
  int head = kvh * 4 + hh;
  s16x8 qf[2];
#pragma unroll
  for (int st = 0; st < 2; ++st)
    qf[st] = *(const s16x8*)&Q[(tokQ + c) * 1024 + head * 64 + st * 32 + g * 8];
  f32x4 aco[4] = {};
  float mrun[4], lrun[4];
#pragma unroll
  for (int r = 0; r < 4; ++r) { mrun[r] = -1e30f; lrun[r] = 0.f; }
  unsigned short* myP = &Ps[w * 1152];

  for (int kt = 0; kt < 32; ++kt) {
    __syncthreads();  // previous iter's LDS reads done
    {
      int tt = t & 511;
      int row = tt >> 3, c0 = (tt & 7) * 8;
      size_t gbase = ((size_t)b * SS + (size_t)kt * 64 + row) * 512 + kvh * 64 + c0;
      if (t < 512) {  // K tile [64 tok][64 d], row-major
        int4 kk = *(const int4*)&KV[gbase];
        *(int4*)&Ks[row * 72 + c0] = kk;
      } else {        // V tile transposed -> VT[d][tok]
        int4 vv = *(const int4*)&KV[gbase + 256];
        const short* vs = (const short*)&vv;
#pragma unroll
        for (int j = 0; j < 8; ++j) VTs[(c0 + j) * 72 + row] = (unsigned short)vs[j];
      }
      int mrow = t >> 4, mc0 = (t & 15) * 4;  // mask tile as bf16
      float4 mv = *(const float4*)&mask[(size_t)b * SS * SS +
                                        ((size_t)qt * 64 + mrow) * SS + (size_t)kt * 64 + mc0];
      ushort4 mo;
      mo.x = f2bf(mv.x); mo.y = f2bf(mv.y); mo.z = f2bf(mv.z); mo.w = f2bf(mv.w);
      *(ushort4*)&Ms[mrow * 72 + mc0] = mo;
    }
    __syncthreads();
    // S = Q K^T  (16 q rows x 64 k)
    f32x4 as[4] = {};
#pragma unroll
    for (int st = 0; st < 2; ++st)
#pragma unroll
      for (int n = 0; n < 4; ++n) {
        s16x8 kb = *(const s16x8*)&Ks[(n * 16 + c) * 72 + st * 32 + g * 8];
        as[n] = mfma_bf16(qf[st], kb, as[n]);
      }
    float sv[4][4];
#pragma unroll
    for (int n = 0; n < 4; ++n)
#pragma unroll
      for (int r = 0; r < 4; ++r)
        sv[n][r] = as[n][r] * 0.125f + bf2f(Ms[(qw * 16 + g * 4 + r) * 72 + n * 16 + c]);
    // online softmax, row = (g*4+r), reduce across 16 lanes of the group
#pragma unroll
    for (int r = 0; r < 4; ++r) {
      float mx = fmaxf(fmaxf(sv[0][r], sv[1][r]), fmaxf(sv[2][r], sv[3][r]));
#pragma unroll
      for (int mm = 1; mm < 16; mm <<= 1) mx = fmaxf(mx, __shfl_xor(mx, mm));
      float mnew = fmaxf(mrun[r], mx);
      float alpha = __expf(mrun[r] - mnew);
      float ps = 0.f;
#pragma unroll
      for (int n = 0; n < 4; ++n) { float p = __expf(sv[n][r] - mnew); sv[n][r] = p; ps += p; }
#pragma unroll
      for (int mm = 1; mm < 16; mm <<= 1) ps += __shfl_xor(ps, mm);
      lrun[r] = lrun[r] * alpha + ps;
      mrun[r] = mnew;
#pragma unroll
      for (int n = 0; n < 4; ++n) {
        aco[n][r] *= alpha;
        myP[(g * 4 + r) * 72 + n * 16 + c] = f2bf(sv[n][r]);
      }
    }
    // wave-private P slab: ds_writes must land before cross-lane ds_reads
    asm volatile("s_waitcnt lgkmcnt(0)" ::: "memory");
    __builtin_amdgcn_sched_barrier(0);
#pragma unroll
    for (int st = 0; st < 2; ++st) {
      s16x8 pa = *(const s16x8*)&myP[c * 72 + st * 32 + g * 8];
#pragma unroll
      for (int n = 0; n < 4; ++n) {
        s16x8 vb = *(const s16x8*)&VTs[(n * 16 + c) * 72 + st * 32 + g * 8];
        aco[n] = mfma_bf16(pa, vb, aco[n]);
      }
    }
  }
#pragma unroll
  for (int n = 0; n < 4; ++n)
#pragma unroll
    for (int r = 0; r < 4; ++r) {
      float v = aco[n][r] / lrun[r];
      Out[(tokQ + g * 4 + r) * 1024 + head * 64 + n * 16 + c] = f2bf(v);
    }
}

extern "C" void kernel_launch(void* const* d_in, const int* in_sizes, int n_in,
                              void* d_out, int out_size, void* d_ws, size_t ws_size,
                              hipStream_t stream) {
  (void)in_sizes; (void)n_in; (void)out_size; (void)ws_size;
  const float* hidden = (const float*)d_in[0];
  const float* kvst   = (const float*)d_in[1];
  const float* maskp  = (const float*)d_in[2];
  const float* ln1    = (const float*)d_in[3];
  const float* ln2    = (const float*)d_in[4];
  const float* Wq     = (const float*)d_in[5];
  const float* Wk     = (const float*)d_in[6];
  const float* Wv     = (const float*)d_in[7];
  const float* Wo     = (const float*)d_in[8];
  const float* Wg     = (const float*)d_in[9];
  const float* Wu     = (const float*)d_in[10];
  const float* Wd     = (const float*)d_in[11];
  float* out = (float*)d_out;

  char* ws = (char*)d_ws;
  size_t off = 0;
  auto alloc = [&](size_t bytes) { char* p = ws + off; off += (bytes + 255) & ~(size_t)255; return p; };
  unsigned short* WTq   = (unsigned short*)alloc((size_t)1024 * 1024 * 2);
  unsigned short* WTkv  = (unsigned short*)alloc((size_t)512 * 1024 * 2);
  unsigned short* WTo   = (unsigned short*)alloc((size_t)1024 * 1024 * 2);
  unsigned short* WTg   = (unsigned short*)alloc((size_t)4096 * 1024 * 2);
  unsigned short* WTu   = (unsigned short*)alloc((size_t)4096 * 1024 * 2);
  unsigned short* WTd   = (unsigned short*)alloc((size_t)1024 * 4096 * 2);
  float* cosT           = (float*)alloc((size_t)2048 * 32 * 4);
  float* sinT           = (float*)alloc((size_t)2048 * 32 * 4);
  unsigned short* hn    = (unsigned short*)alloc((size_t)4096 * 1024 * 2);
  unsigned short* kvn   = (unsigned short*)alloc((size_t)4096 * 1024 * 2);
  unsigned short* Qb    = (unsigned short*)alloc((size_t)4096 * 1024 * 2);
  unsigned short* KVb   = (unsigned short*)alloc((size_t)4096 * 512 * 2);
  float* hid2           = (float*)alloc((size_t)4096 * 1024 * 4);
  unsigned short* inter = (unsigned short*)alloc((size_t)4096 * 4096 * 2);
  unsigned short* attnb = hn;   // hn dead after Q-proj
  unsigned short* h2n   = kvn;  // kvn dead after KV-proj

  // weights -> bf16 transposed
  k_transpose<<<dim3(32, 32), 256, 0, stream>>>(Wq, WTq, 1024, 1024);
  k_transpose<<<dim3(8, 32), 256, 0, stream>>>(Wk, WTkv, 1024, 256);
  k_transpose<<<dim3(8, 32), 256, 0, stream>>>(Wv, WTkv + (size_t)256 * 1024, 1024, 256);
  k_transpose<<<dim3(32, 32), 256, 0, stream>>>(Wo, WTo, 1024, 1024);
  k_transpose<<<dim3(128, 32), 256, 0, stream>>>(Wg, WTg, 1024, 4096);
  k_transpose<<<dim3(128, 32), 256, 0, stream>>>(Wu, WTu, 1024, 4096);
  k_transpose<<<dim3(32, 128), 256, 0, stream>>>(Wd, WTd, 4096, 1024);
  k_rope_tables<<<256, 256, 0, stream>>>(cosT, sinT);
  // norms
  k_rmsnorm<<<4096, 256, 0, stream>>>(hidden, ln1, hn);
  k_rmsnorm<<<4096, 256, 0, stream>>>(kvst, ln1, kvn);
  // projections
  k_gemm<0><<<dim3(8, 32), 256, 0, stream>>>(hn, WTq, 1024, 1024, Qb, nullptr, nullptr, nullptr);
  k_gemm<0><<<dim3(4, 32), 256, 0, stream>>>(kvn, WTkv, 512, 1024, KVb, nullptr, nullptr, nullptr);
  // rope (Q: 16 heads; K: 4 heads, first 256 cols of KVb)
  k_rope<<<2048, 256, 0, stream>>>(Qb, cosT, sinT, 4, 1024);
  k_rope<<<512, 256, 0, stream>>>(KVb, cosT, sinT, 2, 512);
  // attention
  k_attn<<<256, 1024, 0, stream>>>(Qb, KVb, maskp, attnb);
  // O proj + residual
  k_gemm<1><<<dim3(8, 32), 256, 0, stream>>>(attnb, WTo, 1024, 1024, nullptr, hid2, hidden, nullptr);
  // MLP
  k_rmsnorm<<<4096, 256, 0, stream>>>(hid2, ln2, h2n);
  k_gemm<2><<<dim3(32, 32), 256, 0, stream>>>(h2n, WTg, 4096, 1024, inter, nullptr, nullptr, nullptr);
  k_gemm<3><<<dim3(32, 32), 256, 0, stream>>>(h2n, WTu, 4096, 1024, inter, nullptr, nullptr, inter);
  k_gemm<1><<<dim3(8, 32), 256, 0, stream>>>(inter, WTd, 1024, 4096, nullptr, out, hid2, nullptr);
}

// Round 2
// 453.269 us; speedup vs baseline: 1.0995x; 1.0995x over previous
//
#include <hip/hip_runtime.h>
#include <math.h>

#define SS 2048

typedef __attribute__((ext_vector_type(8))) short s16x8;
typedef __attribute__((ext_vector_type(4))) float f32x4;

__device__ __forceinline__ unsigned short f2bf(float f) {
  union { float f; unsigned u; } a; a.f = f;
  unsigned r = a.u + 0x7fffu + ((a.u >> 16) & 1u);   // RNE
  return (unsigned short)(r >> 16);
}
__device__ __forceinline__ float bf2f(unsigned short b) {
  union { unsigned u; float f; } a; a.u = ((unsigned)b) << 16;
  return a.f;
}
__device__ __forceinline__ void async16(void* lds, const void* g) {
  __builtin_amdgcn_global_load_lds(
      (const __attribute__((address_space(1))) unsigned int*)g,
      (__attribute__((address_space(3))) unsigned int*)lds, 16, 0, 0);
}
__device__ __forceinline__ f32x4 mfma_bf16(s16x8 a, s16x8 b, f32x4 c) {
  return __builtin_amdgcn_mfma_f32_16x16x32_bf16(a, b, c, 0, 0, 0);
}

// ---------- transpose + fp32->bf16: WT[n][k] = bf16(W[k][n]) ----------
__global__ __launch_bounds__(256) void k_transpose(const float* __restrict__ W,
                                                   unsigned short* __restrict__ WT,
                                                   int K, int N) {
  __shared__ float tile[32][33];
  int t = threadIdx.x;
  int tx = t & 31, ty = t >> 5;
  int n0 = blockIdx.x * 32, k0 = blockIdx.y * 32;
#pragma unroll
  for (int i = 0; i < 4; ++i)
    tile[ty + 8 * i][tx] = W[(size_t)(k0 + ty + 8 * i) * N + n0 + tx];
  __syncthreads();
#pragma unroll
  for (int i = 0; i < 4; ++i)
    WT[(size_t)(n0 + ty + 8 * i) * K + k0 + tx] = f2bf(tile[tx][ty + 8 * i]);
}

// ---------- V^T precompute: VT[(b*4+kvh)][d=64][s=2048] from QKV cols 1280.. ----------
__global__ __launch_bounds__(256) void k_vtrans(const unsigned short* __restrict__ QKV,
                                                unsigned short* __restrict__ VT) {
  __shared__ unsigned short tile[32][33];
  int t = threadIdx.x, tx = t & 31, ty = t >> 5;
  int s0 = blockIdx.x * 32, d0 = blockIdx.y * 32;
  int bk = blockIdx.z; int b = bk >> 2, kvh = bk & 3;
#pragma unroll
  for (int i = 0; i < 4; ++i)
    tile[ty + 8 * i][tx] =
        QKV[((size_t)b * SS + s0 + ty + 8 * i) * 1536 + 1280 + kvh * 64 + d0 + tx];
  __syncthreads();
#pragma unroll
  for (int i = 0; i < 4; ++i)
    VT[((size_t)bk * 64 + d0 + ty + 8 * i) * SS + s0 + tx] = tile[tx][ty + 8 * i];
}

// ---------- RoPE tables (double precision, once per launch) ----------
__global__ void k_rope_tables(float* __restrict__ cosT, float* __restrict__ sinT) {
  int idx = blockIdx.x * 256 + threadIdx.x;  // 65536 = 2048*32
  int s = idx >> 5, i = idx & 31;
  double ang = (double)s * pow(10000.0, -(double)(2 * i) / 64.0);
  cosT[idx] = (float)cos(ang);
  sinT[idx] = (float)sin(ang);
}

// ---------- RMSNorm fp32 -> bf16 (one block per row, H=1024) ----------
__global__ __launch_bounds__(256) void k_rmsnorm(const float* __restrict__ X,
                                                 const float* __restrict__ Wt,
                                                 unsigned short* __restrict__ Y) {
  int row = blockIdx.x, t = threadIdx.x;
  float4 v = ((const float4*)X)[(size_t)row * 256 + t];
  float ssq = v.x * v.x + v.y * v.y + v.z * v.z + v.w * v.w;
#pragma unroll
  for (int m = 1; m < 64; m <<= 1) ssq += __shfl_xor(ssq, m);
  __shared__ float red[4];
  if ((t & 63) == 0) red[t >> 6] = ssq;
  __syncthreads();
  float sc = rsqrtf((red[0] + red[1] + red[2] + red[3]) * (1.0f / 1024.0f) + 1e-6f);
  float4 wv = ((const float4*)Wt)[t];
  ushort4 o;
  o.x = f2bf(v.x * sc * wv.x); o.y = f2bf(v.y * sc * wv.y);
  o.z = f2bf(v.z * sc * wv.z); o.w = f2bf(v.w * sc * wv.w);
  ((ushort4*)Y)[(size_t)row * 256 + t] = o;
}

// ---------- RoPE in place on QKV buffer; head = blockIdx.y (0..19 -> col h*64) ----------
__global__ __launch_bounds__(256) void k_rope(unsigned short* __restrict__ X,
                                              const float* __restrict__ cosT,
                                              const float* __restrict__ sinT,
                                              int stride) {
  int idx = blockIdx.x * 256 + threadIdx.x;  // tok*8+seg, tok 0..4095
  int seg = idx & 7, tok = idx >> 3;
  int head = blockIdx.y;
  int s = tok & (SS - 1);
  int d0 = seg * 4;
  unsigned short* p = X + (size_t)tok * stride + head * 64;
  ushort4 lo = *(ushort4*)&p[d0];
  ushort4 hi = *(ushort4*)&p[d0 + 32];
  float4 cs = *(const float4*)&cosT[s * 32 + d0];
  float4 sn = *(const float4*)&sinT[s * 32 + d0];
  ushort4 olo, ohi;
  olo.x = f2bf(bf2f(lo.x) * cs.x - bf2f(hi.x) * sn.x);
  olo.y = f2bf(bf2f(lo.y) * cs.y - bf2f(hi.y) * sn.y);
  olo.z = f2bf(bf2f(lo.z) * cs.z - bf2f(hi.z) * sn.z);
  olo.w = f2bf(bf2f(lo.w) * cs.w - bf2f(hi.w) * sn.w);
  ohi.x = f2bf(bf2f(hi.x) * cs.x + bf2f(lo.x) * sn.x);
  ohi.y = f2bf(bf2f(hi.y) * cs.y + bf2f(lo.y) * sn.y);
  ohi.z = f2bf(bf2f(hi.z) * cs.z + bf2f(lo.z) * sn.z);
  ohi.w = f2bf(bf2f(hi.w) * cs.w + bf2f(lo.w) * sn.w);
  *(ushort4*)&p[d0] = olo;
  *(ushort4*)&p[d0 + 32] = ohi;
}

// ---------- GEMM: C[M,N] = A[M,K](bf16) x BT[N,K](bf16), m97 structure ----------
// EPI: 0 = bf16 store, 1 = fp32 store + fp32 residual
template <int EPI>
__global__ __launch_bounds__(256) void k_gemm(const unsigned short* __restrict__ A,
                                              const unsigned short* __restrict__ BT,
                                              int N, int K, int ldc,
                                              unsigned short* Cb,
                                              float* __restrict__ Cf,
                                              const float* __restrict__ Res) {
  __shared__ __align__(16) unsigned short at[128 * 32];
  __shared__ __align__(16) unsigned short bt[128 * 32];
  int t = threadIdx.x, w = t >> 6, l = t & 63;
  int g = l >> 4, c = l & 15;
  int wm = w >> 1, wn = w & 1;
  f32x4 acc[4][4] = {};
  const unsigned short* gA = A + (size_t)(blockIdx.y * 128 + (t >> 2)) * K + (t & 3) * 8;
  const unsigned short* gB = BT + (size_t)(blockIdx.x * 128 + (t >> 2)) * K + (t & 3) * 8;
  unsigned short* dA = &at[w * 512];  // wave-uniform base; HW adds lane*16B
  unsigned short* dB = &bt[w * 512];
  const int nk = K >> 5;
  for (int kt = 0; kt < nk; ++kt) {
    async16(dA, gA);
    async16(dA + 2048, gA + (size_t)64 * K);
    async16(dB, gB);
    async16(dB + 2048, gB + (size_t)64 * K);
    gA += 32; gB += 32;
    __syncthreads();
    s16x8 af[4], bfr[4];
#pragma unroll
    for (int m = 0; m < 4; ++m) af[m] = *(const s16x8*)&at[(wm * 64 + m * 16 + c) * 32 + g * 8];
#pragma unroll
    for (int n = 0; n < 4; ++n) bfr[n] = *(const s16x8*)&bt[(wn * 64 + n * 16 + c) * 32 + g * 8];
#pragma unroll
    for (int m = 0; m < 4; ++m)
#pragma unroll
      for (int n = 0; n < 4; ++n)
        acc[m][n] = mfma_bf16(af[m], bfr[n], acc[m][n]);
    __syncthreads();
  }
  size_t rb = (size_t)blockIdx.y * 128 + wm * 64;
  size_t cbase = (size_t)blockIdx.x * 128 + wn * 64;
#pragma unroll
  for (int m = 0; m < 4; ++m)
#pragma unroll
    for (int n = 0; n < 4; ++n)
#pragma unroll
      for (int r = 0; r < 4; ++r) {
        size_t row = rb + m * 16 + g * 4 + r;      // C row = (lane>>4)*4+reg
        size_t col = cbase + n * 16 + c;           // C col = lane&15
        float v = acc[m][n][r];
        if (EPI == 0) Cb[row * ldc + col] = f2bf(v);
        else Cf[row * ldc + col] = v + Res[row * ldc + col];
      }
}

// ---------- fused gate+up GEMM: inter = silu(A@Wg) * (A@Wu), BM=128 BN=64 ----------
__global__ __launch_bounds__(256) void k_gateup(const unsigned short* __restrict__ A,
                                                const unsigned short* __restrict__ BTg,
                                                const unsigned short* __restrict__ BTu,
                                                unsigned short* __restrict__ Cb) {
  __shared__ __align__(16) unsigned short at[128 * 32];
  __shared__ __align__(16) unsigned short bg[64 * 32];
  __shared__ __align__(16) unsigned short bu[64 * 32];
  int t = threadIdx.x, w = t >> 6, l = t & 63;
  int g = l >> 4, c = l & 15;
  int wm = w >> 1, wn = w & 1;
  f32x4 ag[4][2] = {}, au[4][2] = {};
  const unsigned short* gA = A + (size_t)(blockIdx.y * 128 + (t >> 2)) * 1024 + (t & 3) * 8;
  const unsigned short* gG = BTg + (size_t)(blockIdx.x * 64 + (t >> 2)) * 1024 + (t & 3) * 8;
  const unsigned short* gU = BTu + (size_t)(blockIdx.x * 64 + (t >> 2)) * 1024 + (t & 3) * 8;
  unsigned short* dA = &at[w * 512];
  unsigned short* dG = &bg[w * 512];
  unsigned short* dU = &bu[w * 512];
  for (int kt = 0; kt < 32; ++kt) {
    async16(dA, gA);
    async16(dA + 2048, gA + (size_t)64 * 1024);
    async16(dG, gG);
    async16(dU, gU);
    gA += 32; gG += 32; gU += 32;
    __syncthreads();
    s16x8 af[4], bgf[2], buf_[2];
#pragma unroll
    for (int m = 0; m < 4; ++m) af[m] = *(const s16x8*)&at[(wm * 64 + m * 16 + c) * 32 + g * 8];
#pragma unroll
    for (int n = 0; n < 2; ++n) {
      bgf[n] = *(const s16x8*)&bg[(wn * 32 + n * 16 + c) * 32 + g * 8];
      buf_[n] = *(const s16x8*)&bu[(wn * 32 + n * 16 + c) * 32 + g * 8];
    }
#pragma unroll
    for (int m = 0; m < 4; ++m)
#pragma unroll
      for (int n = 0; n < 2; ++n) {
        ag[m][n] = mfma_bf16(af[m], bgf[n], ag[m][n]);
        au[m][n] = mfma_bf16(af[m], buf_[n], au[m][n]);
      }
    __syncthreads();
  }
  size_t rb = (size_t)blockIdx.y * 128 + wm * 64;
  size_t cb = (size_t)blockIdx.x * 64 + wn * 32;
#pragma unroll
  for (int m = 0; m < 4; ++m)
#pragma unroll
    for (int n = 0; n < 2; ++n)
#pragma unroll
      for (int r = 0; r < 4; ++r) {
        size_t row = rb + m * 16 + g * 4 + r;
        size_t col = cb + n * 16 + c;
        float gv = ag[m][n][r], uv = au[m][n][r];
        Cb[row * 4096 + col] = f2bf(gv / (1.0f + __expf(-gv)) * uv);
      }
}

// ---------- Flash attention, GQA: 8 waves, 32 q-rows/block, reg-prefetch ----------
__global__ __launch_bounds__(512) void k_attn(const unsigned short* __restrict__ Q,
                                              const unsigned short* __restrict__ K,
                                              const unsigned short* __restrict__ VT,
                                              const float* __restrict__ mask,
                                              unsigned short* __restrict__ Out) {
  __shared__ __align__(16) unsigned short Ks[64 * 72];
  __shared__ __align__(16) unsigned short VTs[64 * 72];
  __shared__ __align__(16) unsigned short Ps[8 * 16 * 68];
  int t = threadIdx.x, w = t >> 6, l = t & 63;
  int g = l >> 4, c = l & 15;
  int qw = w >> 2, hh = w & 3;           // qw 0..1 (16 q-rows), hh 0..3 (head in group)
  int blk = blockIdx.x;
  int qt = blk & 63, kvh = (blk >> 6) & 3, b = blk >> 8;
  size_t tokQ = (size_t)b * SS + qt * 32 + qw * 16;
  int head = kvh * 4 + hh;
  s16x8 qf[2];
#pragma unroll
  for (int st = 0; st < 2; ++st)
    qf[st] = *(const s16x8*)&Q[(tokQ + c) * 1536 + head * 64 + st * 32 + g * 8];

  int srow = t >> 3, sc0 = (t & 7) * 8;  // 512 threads: one K slot + one VT slot each
  const unsigned short* gK = K + ((size_t)b * SS + srow) * 1536 + kvh * 64 + sc0;
  const unsigned short* gV = VT + ((size_t)(b * 4 + kvh) * 64 + srow) * SS + sc0;

  int4 rK = *(const int4*)gK;            // tile 0
  int4 rV = *(const int4*)gV;
  *(int4*)&Ks[srow * 72 + sc0] = rK;
  *(int4*)&VTs[srow * 72 + sc0] = rV;

  const float* mrow = mask + (size_t)b * SS * SS + (size_t)(qt * 32 + qw * 16 + g * 4) * SS + c;
  float mcur[4][4], mnxt[4][4];
#pragma unroll
  for (int n = 0; n < 4; ++n)
#pragma unroll
    for (int r = 0; r < 4; ++r) mcur[n][r] = mrow[(size_t)r * SS + n * 16];

  f32x4 aco[4] = {};
  float mrun[4], lrun[4];
#pragma unroll
  for (int r = 0; r < 4; ++r) { mrun[r] = -1e30f; lrun[r] = 0.f; }
  unsigned short* myP = &Ps[w * (16 * 68)];
  __syncthreads();

  for (int kt = 0; kt < 32; ++kt) {
    int nx = kt < 31 ? kt + 1 : 31;
    // prefetch next K/VT tile + next mask tile (consumed after the barrier / next iter)
    rK = *(const int4*)(gK + (size_t)nx * 64 * 1536);
    rV = *(const int4*)(gV + nx * 64);
#pragma unroll
    for (int n = 0; n < 4; ++n)
#pragma unroll
      for (int r = 0; r < 4; ++r) mnxt[n][r] = mrow[(size_t)r * SS + nx * 64 + n * 16];

    // S = Q K^T   (rows q = g*4+r, cols k = n*16+c)
    f32x4 as[4] = {};
#pragma unroll
    for (int st = 0; st < 2; ++st)
#pragma unroll
      for (int n = 0; n < 4; ++n) {
        s16x8 kb = *(const s16x8*)&Ks[(n * 16 + c) * 72 + st * 32 + g * 8];
        as[n] = mfma_bf16(qf[st], kb, as[n]);
      }
    float sv[4][4];
#pragma unroll
    for (int n = 0; n < 4; ++n)
#pragma unroll
      for (int r = 0; r < 4; ++r) sv[n][r] = as[n][r] * 0.125f + mcur[n][r];
    // online softmax: row held by 16 lanes (fixed g), reduce over c via xor 1,2,4,8
#pragma unroll
    for (int r = 0; r < 4; ++r) {
      float mx = fmaxf(fmaxf(sv[0][r], sv[1][r]), fmaxf(sv[2][r], sv[3][r]));
#pragma unroll
      for (int mm = 1; mm < 16; mm <<= 1) mx = fmaxf(mx, __shfl_xor(mx, mm));
      float mnew = fmaxf(mrun[r], mx);
      float alpha = __expf(mrun[r] - mnew);
      float ps = 0.f;
#pragma unroll
      for (int n = 0; n < 4; ++n) { float p = __expf(sv[n][r] - mnew); sv[n][r] = p; ps += p; }
#pragma unroll
      for (int mm = 1; mm < 16; mm <<= 1) ps += __shfl_xor(ps, mm);
      lrun[r] = lrun[r] * alpha + ps;
      mrun[r] = mnew;
#pragma unroll
      for (int n = 0; n < 4; ++n) {
        aco[n][r] *= alpha;
        myP[(g * 4 + r) * 68 + n * 16 + c] = f2bf(sv[n][r]);  // stride 68: 4 groups -> banks {0,8,16,24}
      }
    }
    asm volatile("s_waitcnt lgkmcnt(0)" ::: "memory");  // P writes landed (wave-private slab)
    __builtin_amdgcn_sched_barrier(0);                  // rule #18: keep MFMA below the wait
#pragma unroll
    for (int st = 0; st < 2; ++st) {
      s16x8 pa = *(const s16x8*)&myP[c * 68 + st * 32 + g * 8];
#pragma unroll
      for (int n = 0; n < 4; ++n) {
        s16x8 vb = *(const s16x8*)&VTs[(n * 16 + c) * 72 + st * 32 + g * 8];
        aco[n] = mfma_bf16(pa, vb, aco[n]);
      }
    }
    __syncthreads();                    // all LDS reads of tile kt complete
    if (kt < 31) {
      *(int4*)&Ks[srow * 72 + sc0] = rK;   // write prefetched tile kt+1
      *(int4*)&VTs[srow * 72 + sc0] = rV;
    }
#pragma unroll
    for (int n = 0; n < 4; ++n)
#pragma unroll
      for (int r = 0; r < 4; ++r) mcur[n][r] = mnxt[n][r];
    __syncthreads();
  }
#pragma unroll
  for (int n = 0; n < 4; ++n)
#pragma unroll
    for (int r = 0; r < 4; ++r) {
      float v = aco[n][r] / lrun[r];
      Out[(tokQ + g * 4 + r) * 1024 + head * 64 + n * 16 + c] = f2bf(v);
    }
}

extern "C" void kernel_launch(void* const* d_in, const int* in_sizes, int n_in,
                              void* d_out, int out_size, void* d_ws, size_t ws_size,
                              hipStream_t stream) {
  (void)in_sizes; (void)n_in; (void)out_size; (void)ws_size;
  const float* hidden = (const float*)d_in[0];
  const float* kvst   = (const float*)d_in[1];
  const float* maskp  = (const float*)d_in[2];
  const float* ln1    = (const float*)d_in[3];
  const float* ln2    = (const float*)d_in[4];
  const float* Wq     = (const float*)d_in[5];
  const float* Wk     = (const float*)d_in[6];
  const float* Wv     = (const float*)d_in[7];
  const float* Wo     = (const float*)d_in[8];
  const float* Wg     = (const float*)d_in[9];
  const float* Wu     = (const float*)d_in[10];
  const float* Wd     = (const float*)d_in[11];
  float* out = (float*)d_out;

  char* ws = (char*)d_ws;
  size_t off = 0;
  auto alloc = [&](size_t bytes) { char* p = ws + off; off += (bytes + 255) & ~(size_t)255; return p; };
  unsigned short* WTqkv = (unsigned short*)alloc((size_t)1536 * 1024 * 2);
  unsigned short* WTo   = (unsigned short*)alloc((size_t)1024 * 1024 * 2);
  unsigned short* WTg   = (unsigned short*)alloc((size_t)4096 * 1024 * 2);
  unsigned short* WTu   = (unsigned short*)alloc((size_t)4096 * 1024 * 2);
  unsigned short* WTd   = (unsigned short*)alloc((size_t)1024 * 4096 * 2);
  float* cosT           = (float*)alloc((size_t)2048 * 32 * 4);
  float* sinT           = (float*)alloc((size_t)2048 * 32 * 4);
  unsigned short* hn    = (unsigned short*)alloc((size_t)4096 * 1024 * 2);
  unsigned short* kvn   = (unsigned short*)alloc((size_t)4096 * 1024 * 2);
  unsigned short* QKVb  = (unsigned short*)alloc((size_t)4096 * 1536 * 2);
  unsigned short* VTg   = (unsigned short*)alloc((size_t)8 * 64 * SS * 2);
  float* hid2           = (float*)alloc((size_t)4096 * 1024 * 4);
  unsigned short* inter = (unsigned short*)alloc((size_t)4096 * 4096 * 2);
  unsigned short* attnb = hn;   // hn dead after Q-proj
  unsigned short* h2n   = kvn;  // kvn dead after KV-proj

  // weights -> bf16 transposed (QKV packed: rows 0..1023 = Wq, 1024..1279 = Wk, 1280..1535 = Wv)
  k_transpose<<<dim3(32, 32), 256, 0, stream>>>(Wq, WTqkv, 1024, 1024);
  k_transpose<<<dim3(8, 32), 256, 0, stream>>>(Wk, WTqkv + (size_t)1024 * 1024, 1024, 256);
  k_transpose<<<dim3(8, 32), 256, 0, stream>>>(Wv, WTqkv + (size_t)1280 * 1024, 1024, 256);
  k_transpose<<<dim3(32, 32), 256, 0, stream>>>(Wo, WTo, 1024, 1024);
  k_transpose<<<dim3(128, 32), 256, 0, stream>>>(Wg, WTg, 1024, 4096);
  k_transpose<<<dim3(128, 32), 256, 0, stream>>>(Wu, WTu, 1024, 4096);
  k_transpose<<<dim3(32, 128), 256, 0, stream>>>(Wd, WTd, 4096, 1024);
  k_rope_tables<<<256, 256, 0, stream>>>(cosT, sinT);
  // norms
  k_rmsnorm<<<4096, 256, 0, stream>>>(hidden, ln1, hn);
  k_rmsnorm<<<4096, 256, 0, stream>>>(kvst, ln1, kvn);
  // projections into packed QKV [4096][1536]
  k_gemm<0><<<dim3(8, 32), 256, 0, stream>>>(hn, WTqkv, 1024, 1024, 1536, QKVb, nullptr, nullptr);
  k_gemm<0><<<dim3(4, 32), 256, 0, stream>>>(kvn, WTqkv + (size_t)1024 * 1024, 512, 1024, 1536,
                                             QKVb + 1024, nullptr, nullptr);
  // rope: heads 0..15 = Q, 16..19 = K (col h*64 in packed layout); V untouched
  k_rope<<<dim3(128, 20), 256, 0, stream>>>(QKVb, cosT, sinT, 1536);
  // V^T for conflict-free attention staging
  k_vtrans<<<dim3(64, 2, 8), 256, 0, stream>>>(QKVb, VTg);
  // attention
  k_attn<<<512, 512, 0, stream>>>(QKVb, QKVb + 1024, VTg, maskp, attnb);
  // O proj + residual
  k_gemm<1><<<dim3(8, 32), 256, 0, stream>>>(attnb, WTo, 1024, 1024, 1024, nullptr, hid2, hidden);
  // MLP
  k_rmsnorm<<<4096, 256, 0, stream>>>(hid2, ln2, h2n);
  k_gateup<<<dim3(64, 32), 256, 0, stream>>>(h2n, WTg, WTu, inter);
  k_gemm<1><<<dim3(8, 32), 256, 0, stream>>>(inter, WTd, 1024, 4096, 1024, nullptr, out, hid2);
}

// Round 4
// 402.692 us; speedup vs baseline: 1.2376x; 1.1256x over previous
//
#include <hip/hip_runtime.h>
#include <math.h>

#define SS 2048

typedef __attribute__((ext_vector_type(8))) short s16x8;
typedef __attribute__((ext_vector_type(4))) float f32x4;

__device__ __forceinline__ unsigned short f2bf(float f) {
  union { float f; unsigned u; } a; a.f = f;
  unsigned r = a.u + 0x7fffu + ((a.u >> 16) & 1u);   // RNE
  return (unsigned short)(r >> 16);
}
__device__ __forceinline__ float bf2f(unsigned short b) {
  union { unsigned u; float f; } a; a.u = ((unsigned)b) << 16;
  return a.f;
}
__device__ __forceinline__ void async16(void* lds, const void* g) {
  __builtin_amdgcn_global_load_lds(
      (const __attribute__((address_space(1))) unsigned int*)g,
      (__attribute__((address_space(3))) unsigned int*)lds, 16, 0, 0);
}
__device__ __forceinline__ f32x4 mfma_bf16(s16x8 a, s16x8 b, f32x4 c) {
  return __builtin_amdgcn_mfma_f32_16x16x32_bf16(a, b, c, 0, 0, 0);
}

// DPP cross-lane within 16-lane rows (VALU pipe, no LDS latency).
// ctrl must be a compile-time constant -> template parameter.
template <int CTRL>
__device__ __forceinline__ float fdpp(float x) {
  union { float f; int i; } a; a.f = x;
  a.i = __builtin_amdgcn_update_dpp(0, a.i, CTRL, 0xF, 0xF, true);
  return a.f;
}
// reduce across the 16 lanes of each aligned 16-lane group:
// xor1 (quad_perm 1,0,3,2) -> xor2 (quad_perm 2,3,0,1) -> half_mirror -> mirror
__device__ __forceinline__ float red16max(float x) {
  x = fmaxf(x, fdpp<0xB1>(x));
  x = fmaxf(x, fdpp<0x4E>(x));
  x = fmaxf(x, fdpp<0x141>(x));
  x = fmaxf(x, fdpp<0x140>(x));
  return x;
}
__device__ __forceinline__ float red16sum(float x) {
  x += fdpp<0xB1>(x);
  x += fdpp<0x4E>(x);
  x += fdpp<0x141>(x);
  x += fdpp<0x140>(x);
  return x;
}

// ---------- transpose + fp32->bf16: WT[n][k] = bf16(W[k][n]) ----------
__global__ __launch_bounds__(256) void k_transpose(const float* __restrict__ W,
                                                   unsigned short* __restrict__ WT,
                                                   int K, int N) {
  __shared__ float tile[32][33];
  int t = threadIdx.x;
  int tx = t & 31, ty = t >> 5;
  int n0 = blockIdx.x * 32, k0 = blockIdx.y * 32;
#pragma unroll
  for (int i = 0; i < 4; ++i)
    tile[ty + 8 * i][tx] = W[(size_t)(k0 + ty + 8 * i) * N + n0 + tx];
  __syncthreads();
#pragma unroll
  for (int i = 0; i < 4; ++i)
    WT[(size_t)(n0 + ty + 8 * i) * K + k0 + tx] = f2bf(tile[tx][ty + 8 * i]);
}

// ---------- V^T precompute: VT[(b*4+kvh)][d=64][s=2048] from QKV cols 1280.. ----------
__global__ __launch_bounds__(256) void k_vtrans(const unsigned short* __restrict__ QKV,
                                                unsigned short* __restrict__ VT) {
  __shared__ unsigned short tile[32][33];
  int t = threadIdx.x, tx = t & 31, ty = t >> 5;
  int s0 = blockIdx.x * 32, d0 = blockIdx.y * 32;
  int bk = blockIdx.z; int b = bk >> 2, kvh = bk & 3;
#pragma unroll
  for (int i = 0; i < 4; ++i)
    tile[ty + 8 * i][tx] =
        QKV[((size_t)b * SS + s0 + ty + 8 * i) * 1536 + 1280 + kvh * 64 + d0 + tx];
  __syncthreads();
#pragma unroll
  for (int i = 0; i < 4; ++i)
    VT[((size_t)bk * 64 + d0 + ty + 8 * i) * SS + s0 + tx] = tile[tx][ty + 8 * i];
}

// ---------- RoPE tables (double precision, once per launch) ----------
__global__ void k_rope_tables(float* __restrict__ cosT, float* __restrict__ sinT) {
  int idx = blockIdx.x * 256 + threadIdx.x;  // 65536 = 2048*32
  int s = idx >> 5, i = idx & 31;
  double ang = (double)s * pow(10000.0, -(double)(2 * i) / 64.0);
  cosT[idx] = (float)cos(ang);
  sinT[idx] = (float)sin(ang);
}

// ---------- RMSNorm fp32 -> bf16 (one block per row, H=1024) ----------
__global__ __launch_bounds__(256) void k_rmsnorm(const float* __restrict__ X,
                                                 const float* __restrict__ Wt,
                                                 unsigned short* __restrict__ Y) {
  int row = blockIdx.x, t = threadIdx.x;
  float4 v = ((const float4*)X)[(size_t)row * 256 + t];
  float ssq = v.x * v.x + v.y * v.y + v.z * v.z + v.w * v.w;
#pragma unroll
  for (int m = 1; m < 64; m <<= 1) ssq += __shfl_xor(ssq, m);
  __shared__ float red[4];
  if ((t & 63) == 0) red[t >> 6] = ssq;
  __syncthreads();
  float sc = rsqrtf((red[0] + red[1] + red[2] + red[3]) * (1.0f / 1024.0f) + 1e-6f);
  float4 wv = ((const float4*)Wt)[t];
  ushort4 o;
  o.x = f2bf(v.x * sc * wv.x); o.y = f2bf(v.y * sc * wv.y);
  o.z = f2bf(v.z * sc * wv.z); o.w = f2bf(v.w * sc * wv.w);
  ((ushort4*)Y)[(size_t)row * 256 + t] = o;
}

// ---------- RoPE in place on QKV buffer; head = blockIdx.y ----------
__global__ __launch_bounds__(256) void k_rope(unsigned short* __restrict__ X,
                                              const float* __restrict__ cosT,
                                              const float* __restrict__ sinT,
                                              int stride) {
  int idx = blockIdx.x * 256 + threadIdx.x;  // tok*8+seg, tok 0..4095
  int seg = idx & 7, tok = idx >> 3;
  int head = blockIdx.y;
  int s = tok & (SS - 1);
  int d0 = seg * 4;
  unsigned short* p = X + (size_t)tok * stride + head * 64;
  ushort4 lo = *(ushort4*)&p[d0];
  ushort4 hi = *(ushort4*)&p[d0 + 32];
  float4 cs = *(const float4*)&cosT[s * 32 + d0];
  float4 sn = *(const float4*)&sinT[s * 32 + d0];
  ushort4 olo, ohi;
  olo.x = f2bf(bf2f(lo.x) * cs.x - bf2f(hi.x) * sn.x);
  olo.y = f2bf(bf2f(lo.y) * cs.y - bf2f(hi.y) * sn.y);
  olo.z = f2bf(bf2f(lo.z) * cs.z - bf2f(hi.z) * sn.z);
  olo.w = f2bf(bf2f(lo.w) * cs.w - bf2f(hi.w) * sn.w);
  ohi.x = f2bf(bf2f(hi.x) * cs.x + bf2f(lo.x) * sn.x);
  ohi.y = f2bf(bf2f(hi.y) * cs.y + bf2f(lo.y) * sn.y);
  ohi.z = f2bf(bf2f(hi.z) * cs.z + bf2f(lo.z) * sn.z);
  ohi.w = f2bf(bf2f(hi.w) * cs.w + bf2f(lo.w) * sn.w);
  *(ushort4*)&p[d0] = olo;
  *(ushort4*)&p[d0 + 32] = ohi;
}

// ---------- GEMM: C[M,N] = A[M,K](bf16) x BT[N,K](bf16), m97 structure ----------
// EPI: 0 = bf16 store, 1 = fp32 store + fp32 residual
template <int EPI>
__global__ __launch_bounds__(256) void k_gemm(const unsigned short* __restrict__ A,
                                              const unsigned short* __restrict__ BT,
                                              int N, int K, int ldc,
                                              unsigned short* Cb,
                                              float* __restrict__ Cf,
                                              const float* __restrict__ Res) {
  __shared__ __align__(16) unsigned short at[128 * 32];
  __shared__ __align__(16) unsigned short bt[128 * 32];
  int t = threadIdx.x, w = t >> 6, l = t & 63;
  int g = l >> 4, c = l & 15;
  int wm = w >> 1, wn = w & 1;
  f32x4 acc[4][4] = {};
  const unsigned short* gA = A + (size_t)(blockIdx.y * 128 + (t >> 2)) * K + (t & 3) * 8;
  const unsigned short* gB = BT + (size_t)(blockIdx.x * 128 + (t >> 2)) * K + (t & 3) * 8;
  unsigned short* dA = &at[w * 512];  // wave-uniform base; HW adds lane*16B
  unsigned short* dB = &bt[w * 512];
  const int nk = K >> 5;
  for (int kt = 0; kt < nk; ++kt) {
    async16(dA, gA);
    async16(dA + 2048, gA + (size_t)64 * K);
    async16(dB, gB);
    async16(dB + 2048, gB + (size_t)64 * K);
    gA += 32; gB += 32;
    __syncthreads();
    s16x8 af[4], bfr[4];
#pragma unroll
    for (int m = 0; m < 4; ++m) af[m] = *(const s16x8*)&at[(wm * 64 + m * 16 + c) * 32 + g * 8];
#pragma unroll
    for (int n = 0; n < 4; ++n) bfr[n] = *(const s16x8*)&bt[(wn * 64 + n * 16 + c) * 32 + g * 8];
#pragma unroll
    for (int m = 0; m < 4; ++m)
#pragma unroll
      for (int n = 0; n < 4; ++n)
        acc[m][n] = mfma_bf16(af[m], bfr[n], acc[m][n]);
    __syncthreads();
  }
  size_t rb = (size_t)blockIdx.y * 128 + wm * 64;
  size_t cbase = (size_t)blockIdx.x * 128 + wn * 64;
#pragma unroll
  for (int m = 0; m < 4; ++m)
#pragma unroll
    for (int n = 0; n < 4; ++n)
#pragma unroll
      for (int r = 0; r < 4; ++r) {
        size_t row = rb + m * 16 + g * 4 + r;      // C row = (lane>>4)*4+reg
        size_t col = cbase + n * 16 + c;           // C col = lane&15
        float v = acc[m][n][r];
        if (EPI == 0) Cb[row * ldc + col] = f2bf(v);
        else Cf[row * ldc + col] = v + Res[row * ldc + col];
      }
}

// ---------- fused gate+up GEMM: inter = silu(A@Wg) * (A@Wu), BM=128 BN=64 ----------
__global__ __launch_bounds__(256) void k_gateup(const unsigned short* __restrict__ A,
                                                const unsigned short* __restrict__ BTg,
                                                const unsigned short* __restrict__ BTu,
                                                unsigned short* __restrict__ Cb) {
  __shared__ __align__(16) unsigned short at[128 * 32];
  __shared__ __align__(16) unsigned short bg[64 * 32];
  __shared__ __align__(16) unsigned short bu[64 * 32];
  int t = threadIdx.x, w = t >> 6, l = t & 63;
  int g = l >> 4, c = l & 15;
  int wm = w >> 1, wn = w & 1;
  f32x4 ag[4][2] = {}, au[4][2] = {};
  const unsigned short* gA = A + (size_t)(blockIdx.y * 128 + (t >> 2)) * 1024 + (t & 3) * 8;
  const unsigned short* gG = BTg + (size_t)(blockIdx.x * 64 + (t >> 2)) * 1024 + (t & 3) * 8;
  const unsigned short* gU = BTu + (size_t)(blockIdx.x * 64 + (t >> 2)) * 1024 + (t & 3) * 8;
  unsigned short* dA = &at[w * 512];
  unsigned short* dG = &bg[w * 512];
  unsigned short* dU = &bu[w * 512];
  for (int kt = 0; kt < 32; ++kt) {
    async16(dA, gA);
    async16(dA + 2048, gA + (size_t)64 * 1024);
    async16(dG, gG);
    async16(dU, gU);
    gA += 32; gG += 32; gU += 32;
    __syncthreads();
    s16x8 af[4], bgf[2], buf_[2];
#pragma unroll
    for (int m = 0; m < 4; ++m) af[m] = *(const s16x8*)&at[(wm * 64 + m * 16 + c) * 32 + g * 8];
#pragma unroll
    for (int n = 0; n < 2; ++n) {
      bgf[n] = *(const s16x8*)&bg[(wn * 32 + n * 16 + c) * 32 + g * 8];
      buf_[n] = *(const s16x8*)&bu[(wn * 32 + n * 16 + c) * 32 + g * 8];
    }
#pragma unroll
    for (int m = 0; m < 4; ++m)
#pragma unroll
      for (int n = 0; n < 2; ++n) {
        ag[m][n] = mfma_bf16(af[m], bgf[n], ag[m][n]);
        au[m][n] = mfma_bf16(af[m], buf_[n], au[m][n]);
      }
    __syncthreads();
  }
  size_t rb = (size_t)blockIdx.y * 128 + wm * 64;
  size_t cb = (size_t)blockIdx.x * 64 + wn * 32;
#pragma unroll
  for (int m = 0; m < 4; ++m)
#pragma unroll
    for (int n = 0; n < 2; ++n)
#pragma unroll
      for (int r = 0; r < 4; ++r) {
        size_t row = rb + m * 16 + g * 4 + r;
        size_t col = cb + n * 16 + c;
        float gv = ag[m][n][r], uv = au[m][n][r];
        Cb[row * 4096 + col] = f2bf(gv / (1.0f + __expf(-gv)) * uv);
      }
}

// ---------- Flash attention: 8 waves, dbuf swizzled K/VT tiles, DPP softmax ----------
// Swizzle: [64 rows][64 cols] bf16, 16B block index ^= (row&7): every b128 read
// instruction hits each bank exactly 8x (the wave64 minimum) -> conflict-free.
__global__ __launch_bounds__(512) void k_attn(const unsigned short* __restrict__ Q,
                                              const unsigned short* __restrict__ K,
                                              const unsigned short* __restrict__ VT,
                                              const float* __restrict__ mask,
                                              unsigned short* __restrict__ Out) {
  __shared__ __align__(16) unsigned short Ks[2][64 * 64];
  __shared__ __align__(16) unsigned short VTs[2][64 * 64];
  __shared__ __align__(16) unsigned short Ps[8 * 16 * 68];
  int t = threadIdx.x, w = t >> 6, l = t & 63;
  int g = l >> 4, c = l & 15;
  int qw = w >> 2, hh = w & 3;           // qw 0..1 (16 q-rows), hh 0..3 (head in group)
  int blk = blockIdx.x;
  int qt = blk & 63, kvh = (blk >> 6) & 3, b = blk >> 8;
  size_t tokQ = (size_t)b * SS + qt * 32 + qw * 16;
  int head = kvh * 4 + hh;
  s16x8 qf[2];
#pragma unroll
  for (int st = 0; st < 2; ++st)
    qf[st] = *(const s16x8*)&Q[(tokQ + c) * 1536 + head * 64 + st * 32 + g * 8];

  // staging: 512 threads, each one 16B slot of K + one of VT
  int srow = t >> 3;
  int soff = srow * 64 + (((t & 7) ^ (srow & 7)) << 3);  // swizzled LDS short-offset
  const unsigned short* gK = K + ((size_t)b * SS + srow) * 1536 + kvh * 64 + (t & 7) * 8;
  const unsigned short* gV = VT + ((size_t)(b * 4 + kvh) * 64 + srow) * SS + (t & 7) * 8;

  int4 rK = *(const int4*)gK;            // tile 0
  int4 rV = *(const int4*)gV;
  *(int4*)&Ks[0][soff] = rK;
  *(int4*)&VTs[0][soff] = rV;

  const float* mrow = mask + (size_t)b * SS * SS + (size_t)(qt * 32 + qw * 16 + g * 4) * SS + c;
  float mcur[4][4], mnxt[4][4];
#pragma unroll
  for (int n = 0; n < 4; ++n)
#pragma unroll
    for (int r = 0; r < 4; ++r) mcur[n][r] = mrow[(size_t)r * SS + n * 16];

  f32x4 aco[4] = {};
  float mrun[4], lrun[4];
#pragma unroll
  for (int r = 0; r < 4; ++r) { mrun[r] = -1e30f; lrun[r] = 0.f; }
  unsigned short* myP = &Ps[w * (16 * 68)];
  __syncthreads();

  for (int kt = 0; kt < 32; ++kt) {
    const unsigned short* Kc = Ks[kt & 1];
    const unsigned short* Vc = VTs[kt & 1];
    int nx = kt < 31 ? kt + 1 : 31;
    // prefetch next K/VT tile + next mask tile into registers
    rK = *(const int4*)(gK + (size_t)nx * 64 * 1536);
    rV = *(const int4*)(gV + nx * 64);
#pragma unroll
    for (int n = 0; n < 4; ++n)
#pragma unroll
      for (int r = 0; r < 4; ++r) mnxt[n][r] = mrow[(size_t)r * SS + nx * 64 + n * 16];

    // S = Q K^T   (rows q = g*4+r, cols k = n*16+c)
    f32x4 as[4] = {};
    __builtin_amdgcn_s_setprio(1);
#pragma unroll
    for (int st = 0; st < 2; ++st)
#pragma unroll
      for (int n = 0; n < 4; ++n) {
        s16x8 kb = *(const s16x8*)&Kc[(n * 16 + c) * 64 + (((st * 4 + g) ^ (c & 7)) << 3)];
        as[n] = mfma_bf16(qf[st], kb, as[n]);
      }
    __builtin_amdgcn_s_setprio(0);
    float sv[4][4];
#pragma unroll
    for (int n = 0; n < 4; ++n)
#pragma unroll
      for (int r = 0; r < 4; ++r) sv[n][r] = as[n][r] * 0.125f + mcur[n][r];
    // online softmax: row q = g*4+r lives in the aligned 16-lane group g; DPP reduce
#pragma unroll
    for (int r = 0; r < 4; ++r) {
      float mx = fmaxf(fmaxf(sv[0][r], sv[1][r]), fmaxf(sv[2][r], sv[3][r]));
      mx = red16max(mx);
      float mnew = fmaxf(mrun[r], mx);
      float alpha = __expf(mrun[r] - mnew);
      float ps = 0.f;
#pragma unroll
      for (int n = 0; n < 4; ++n) { float p = __expf(sv[n][r] - mnew); sv[n][r] = p; ps += p; }
      ps = red16sum(ps);
      lrun[r] = lrun[r] * alpha + ps;
      mrun[r] = mnew;
#pragma unroll
      for (int n = 0; n < 4; ++n) {
        aco[n][r] *= alpha;
        myP[(g * 4 + r) * 68 + n * 16 + c] = f2bf(sv[n][r]);  // stride 68 -> conflict-free
      }
    }
    asm volatile("s_waitcnt lgkmcnt(0)" ::: "memory");  // P writes landed (wave-private slab)
    __builtin_amdgcn_sched_barrier(0);                  // rule #18: keep MFMA below the wait
    __builtin_amdgcn_s_setprio(1);
#pragma unroll
    for (int st = 0; st < 2; ++st) {
      s16x8 pa = *(const s16x8*)&myP[c * 68 + st * 32 + g * 8];
#pragma unroll
      for (int n = 0; n < 4; ++n) {
        s16x8 vb = *(const s16x8*)&Vc[(n * 16 + c) * 64 + (((st * 4 + g) ^ (c & 7)) << 3)];
        aco[n] = mfma_bf16(pa, vb, aco[n]);
      }
    }
    __builtin_amdgcn_s_setprio(0);
    if (kt < 31) {                       // write prefetched tile kt+1 to the other buffer
      *(int4*)&Ks[(kt + 1) & 1][soff] = rK;
      *(int4*)&VTs[(kt + 1) & 1][soff] = rV;
    }
#pragma unroll
    for (int n = 0; n < 4; ++n)
#pragma unroll
      for (int r = 0; r < 4; ++r) mcur[n][r] = mnxt[n][r];
    __syncthreads();                     // single barrier per kt (dbuf)
  }
#pragma unroll
  for (int n = 0; n < 4; ++n)
#pragma unroll
    for (int r = 0; r < 4; ++r) {
      float v = aco[n][r] / lrun[r];
      Out[(tokQ + g * 4 + r) * 1024 + head * 64 + n * 16 + c] = f2bf(v);
    }
}

extern "C" void kernel_launch(void* const* d_in, const int* in_sizes, int n_in,
                              void* d_out, int out_size, void* d_ws, size_t ws_size,
                              hipStream_t stream) {
  (void)in_sizes; (void)n_in; (void)out_size; (void)ws_size;
  const float* hidden = (const float*)d_in[0];
  const float* kvst   = (const float*)d_in[1];
  const float* maskp  = (const float*)d_in[2];
  const float* ln1    = (const float*)d_in[3];
  const float* ln2    = (const float*)d_in[4];
  const float* Wq     = (const float*)d_in[5];
  const float* Wk     = (const float*)d_in[6];
  const float* Wv     = (const float*)d_in[7];
  const float* Wo     = (const float*)d_in[8];
  const float* Wg     = (const float*)d_in[9];
  const float* Wu     = (const float*)d_in[10];
  const float* Wd     = (const float*)d_in[11];
  float* out = (float*)d_out;

  char* ws = (char*)d_ws;
  size_t off = 0;
  auto alloc = [&](size_t bytes) { char* p = ws + off; off += (bytes + 255) & ~(size_t)255; return p; };
  unsigned short* WTqkv = (unsigned short*)alloc((size_t)1536 * 1024 * 2);
  unsigned short* WTo   = (unsigned short*)alloc((size_t)1024 * 1024 * 2);
  unsigned short* WTg   = (unsigned short*)alloc((size_t)4096 * 1024 * 2);
  unsigned short* WTu   = (unsigned short*)alloc((size_t)4096 * 1024 * 2);
  unsigned short* WTd   = (unsigned short*)alloc((size_t)1024 * 4096 * 2);
  float* cosT           = (float*)alloc((size_t)2048 * 32 * 4);
  float* sinT           = (float*)alloc((size_t)2048 * 32 * 4);
  unsigned short* hn    = (unsigned short*)alloc((size_t)4096 * 1024 * 2);
  unsigned short* kvn   = (unsigned short*)alloc((size_t)4096 * 1024 * 2);
  unsigned short* QKVb  = (unsigned short*)alloc((size_t)4096 * 1536 * 2);
  unsigned short* VTg   = (unsigned short*)alloc((size_t)8 * 64 * SS * 2);
  float* hid2           = (float*)alloc((size_t)4096 * 1024 * 4);
  unsigned short* inter = (unsigned short*)alloc((size_t)4096 * 4096 * 2);
  unsigned short* attnb = hn;   // hn dead after Q-proj
  unsigned short* h2n   = kvn;  // kvn dead after KV-proj

  // weights -> bf16 transposed (QKV packed: rows 0..1023 = Wq, 1024..1279 = Wk, 1280..1535 = Wv)
  k_transpose<<<dim3(32, 32), 256, 0, stream>>>(Wq, WTqkv, 1024, 1024);
  k_transpose<<<dim3(8, 32), 256, 0, stream>>>(Wk, WTqkv + (size_t)1024 * 1024, 1024, 256);
  k_transpose<<<dim3(8, 32), 256, 0, stream>>>(Wv, WTqkv + (size_t)1280 * 1024, 1024, 256);
  k_transpose<<<dim3(32, 32), 256, 0, stream>>>(Wo, WTo, 1024, 1024);
  k_transpose<<<dim3(128, 32), 256, 0, stream>>>(Wg, WTg, 1024, 4096);
  k_transpose<<<dim3(128, 32), 256, 0, stream>>>(Wu, WTu, 1024, 4096);
  k_transpose<<<dim3(32, 128), 256, 0, stream>>>(Wd, WTd, 4096, 1024);
  k_rope_tables<<<256, 256, 0, stream>>>(cosT, sinT);
  // norms
  k_rmsnorm<<<4096, 256, 0, stream>>>(hidden, ln1, hn);
  k_rmsnorm<<<4096, 256, 0, stream>>>(kvst, ln1, kvn);
  // projections into packed QKV [4096][1536]
  k_gemm<0><<<dim3(8, 32), 256, 0, stream>>>(hn, WTqkv, 1024, 1024, 1536, QKVb, nullptr, nullptr);
  k_gemm<0><<<dim3(4, 32), 256, 0, stream>>>(kvn, WTqkv + (size_t)1024 * 1024, 512, 1024, 1536,
                                             QKVb + 1024, nullptr, nullptr);
  // rope: heads 0..15 = Q, 16..19 = K (col h*64 in packed layout); V untouched
  k_rope<<<dim3(128, 20), 256, 0, stream>>>(QKVb, cosT, sinT, 1536);
  // V^T for conflict-free attention staging
  k_vtrans<<<dim3(64, 2, 8), 256, 0, stream>>>(QKVb, VTg);
  // attention
  k_attn<<<512, 512, 0, stream>>>(QKVb, QKVb + 1024, VTg, maskp, attnb);
  // O proj + residual
  k_gemm<1><<<dim3(8, 32), 256, 0, stream>>>(attnb, WTo, 1024, 1024, 1024, nullptr, hid2, hidden);
  // MLP
  k_rmsnorm<<<4096, 256, 0, stream>>>(hid2, ln2, h2n);
  k_gateup<<<dim3(64, 32), 256, 0, stream>>>(h2n, WTg, WTu, inter);
  k_gemm<1><<<dim3(8, 32), 256, 0, stream>>>(inter, WTd, 1024, 4096, 1024, nullptr, out, hid2);
}

// Round 5
// 401.329 us; speedup vs baseline: 1.2418x; 1.0034x over previous
//
#include <hip/hip_runtime.h>
#include <math.h>

#define SS 2048

typedef __attribute__((ext_vector_type(8))) short s16x8;
typedef __attribute__((ext_vector_type(4))) float f32x4;

__device__ __forceinline__ unsigned short f2bf(float f) {
  union { float f; unsigned u; } a; a.f = f;
  unsigned r = a.u + 0x7fffu + ((a.u >> 16) & 1u);   // RNE
  return (unsigned short)(r >> 16);
}
__device__ __forceinline__ float bf2f(unsigned short b) {
  union { unsigned u; float f; } a; a.u = ((unsigned)b) << 16;
  return a.f;
}
// single-instruction f32->bf16 (RNE) via v_cvt_pk_bf16_f32 (T12 recipe)
__device__ __forceinline__ unsigned short cvt1(float f) {
  unsigned v;
  asm("v_cvt_pk_bf16_f32 %0, %1, %1" : "=v"(v) : "v"(f));
  return (unsigned short)v;
}
// raw v_exp_f32 = 2^x (ISA: exp is base-2); inputs here are <= +8 so no range fixup needed
__device__ __forceinline__ float fexp2(float x) {
  float r; asm("v_exp_f32 %0, %1" : "=v"(r) : "v"(x)); return r;
}
__device__ __forceinline__ void async16(void* lds, const void* g) {
  __builtin_amdgcn_global_load_lds(
      (const __attribute__((address_space(1))) unsigned int*)g,
      (__attribute__((address_space(3))) unsigned int*)lds, 16, 0, 0);
}
__device__ __forceinline__ f32x4 mfma_bf16(s16x8 a, s16x8 b, f32x4 c) {
  return __builtin_amdgcn_mfma_f32_16x16x32_bf16(a, b, c, 0, 0, 0);
}

// DPP cross-lane within 16-lane rows (VALU pipe, no LDS latency).
template <int CTRL>
__device__ __forceinline__ float fdpp(float x) {
  union { float f; int i; } a; a.f = x;
  a.i = __builtin_amdgcn_update_dpp(0, a.i, CTRL, 0xF, 0xF, true);
  return a.f;
}
// reduce across the 16 lanes of each aligned 16-lane group:
// xor1 (quad_perm 1,0,3,2) -> xor2 (quad_perm 2,3,0,1) -> half_mirror -> mirror
__device__ __forceinline__ float red16max(float x) {
  x = fmaxf(x, fdpp<0xB1>(x));
  x = fmaxf(x, fdpp<0x4E>(x));
  x = fmaxf(x, fdpp<0x141>(x));
  x = fmaxf(x, fdpp<0x140>(x));
  return x;
}
__device__ __forceinline__ float red16sum(float x) {
  x += fdpp<0xB1>(x);
  x += fdpp<0x4E>(x);
  x += fdpp<0x141>(x);
  x += fdpp<0x140>(x);
  return x;
}

// ---------- transpose + fp32->bf16: WT[n][k] = bf16(W[k][n]) ----------
__global__ __launch_bounds__(256) void k_transpose(const float* __restrict__ W,
                                                   unsigned short* __restrict__ WT,
                                                   int K, int N) {
  __shared__ float tile[32][33];
  int t = threadIdx.x;
  int tx = t & 31, ty = t >> 5;
  int n0 = blockIdx.x * 32, k0 = blockIdx.y * 32;
#pragma unroll
  for (int i = 0; i < 4; ++i)
    tile[ty + 8 * i][tx] = W[(size_t)(k0 + ty + 8 * i) * N + n0 + tx];
  __syncthreads();
#pragma unroll
  for (int i = 0; i < 4; ++i)
    WT[(size_t)(n0 + ty + 8 * i) * K + k0 + tx] = f2bf(tile[tx][ty + 8 * i]);
}

// ---------- V^T precompute: VT[(b*4+kvh)][d=64][s=2048] from QKV cols 1280.. ----------
__global__ __launch_bounds__(256) void k_vtrans(const unsigned short* __restrict__ QKV,
                                                unsigned short* __restrict__ VT) {
  __shared__ unsigned short tile[32][33];
  int t = threadIdx.x, tx = t & 31, ty = t >> 5;
  int s0 = blockIdx.x * 32, d0 = blockIdx.y * 32;
  int bk = blockIdx.z; int b = bk >> 2, kvh = bk & 3;
#pragma unroll
  for (int i = 0; i < 4; ++i)
    tile[ty + 8 * i][tx] =
        QKV[((size_t)b * SS + s0 + ty + 8 * i) * 1536 + 1280 + kvh * 64 + d0 + tx];
  __syncthreads();
#pragma unroll
  for (int i = 0; i < 4; ++i)
    VT[((size_t)bk * 64 + d0 + ty + 8 * i) * SS + s0 + tx] = tile[tx][ty + 8 * i];
}

// ---------- RoPE tables (double precision, once per launch) ----------
__global__ void k_rope_tables(float* __restrict__ cosT, float* __restrict__ sinT) {
  int idx = blockIdx.x * 256 + threadIdx.x;  // 65536 = 2048*32
  int s = idx >> 5, i = idx & 31;
  double ang = (double)s * pow(10000.0, -(double)(2 * i) / 64.0);
  cosT[idx] = (float)cos(ang);
  sinT[idx] = (float)sin(ang);
}

// ---------- RMSNorm fp32 -> bf16 (one block per row, H=1024) ----------
__global__ __launch_bounds__(256) void k_rmsnorm(const float* __restrict__ X,
                                                 const float* __restrict__ Wt,
                                                 unsigned short* __restrict__ Y) {
  int row = blockIdx.x, t = threadIdx.x;
  float4 v = ((const float4*)X)[(size_t)row * 256 + t];
  float ssq = v.x * v.x + v.y * v.y + v.z * v.z + v.w * v.w;
#pragma unroll
  for (int m = 1; m < 64; m <<= 1) ssq += __shfl_xor(ssq, m);
  __shared__ float red[4];
  if ((t & 63) == 0) red[t >> 6] = ssq;
  __syncthreads();
  float sc = rsqrtf((red[0] + red[1] + red[2] + red[3]) * (1.0f / 1024.0f) + 1e-6f);
  float4 wv = ((const float4*)Wt)[t];
  ushort4 o;
  o.x = f2bf(v.x * sc * wv.x); o.y = f2bf(v.y * sc * wv.y);
  o.z = f2bf(v.z * sc * wv.z); o.w = f2bf(v.w * sc * wv.w);
  ((ushort4*)Y)[(size_t)row * 256 + t] = o;
}

// ---------- RoPE in place on QKV buffer; head = blockIdx.y ----------
__global__ __launch_bounds__(256) void k_rope(unsigned short* __restrict__ X,
                                              const float* __restrict__ cosT,
                                              const float* __restrict__ sinT,
                                              int stride) {
  int idx = blockIdx.x * 256 + threadIdx.x;  // tok*8+seg, tok 0..4095
  int seg = idx & 7, tok = idx >> 3;
  int head = blockIdx.y;
  int s = tok & (SS - 1);
  int d0 = seg * 4;
  unsigned short* p = X + (size_t)tok * stride + head * 64;
  ushort4 lo = *(ushort4*)&p[d0];
  ushort4 hi = *(ushort4*)&p[d0 + 32];
  float4 cs = *(const float4*)&cosT[s * 32 + d0];
  float4 sn = *(const float4*)&sinT[s * 32 + d0];
  ushort4 olo, ohi;
  olo.x = f2bf(bf2f(lo.x) * cs.x - bf2f(hi.x) * sn.x);
  olo.y = f2bf(bf2f(lo.y) * cs.y - bf2f(hi.y) * sn.y);
  olo.z = f2bf(bf2f(lo.z) * cs.z - bf2f(hi.z) * sn.z);
  olo.w = f2bf(bf2f(lo.w) * cs.w - bf2f(hi.w) * sn.w);
  ohi.x = f2bf(bf2f(hi.x) * cs.x + bf2f(lo.x) * sn.x);
  ohi.y = f2bf(bf2f(hi.y) * cs.y + bf2f(lo.y) * sn.y);
  ohi.z = f2bf(bf2f(hi.z) * cs.z + bf2f(lo.z) * sn.z);
  ohi.w = f2bf(bf2f(hi.w) * cs.w + bf2f(lo.w) * sn.w);
  *(ushort4*)&p[d0] = olo;
  *(ushort4*)&p[d0 + 32] = ohi;
}

// ---------- GEMM: C[M,N] = A[M,K](bf16) x BT[N,K](bf16), m97 structure ----------
// EPI: 0 = bf16 store, 1 = fp32 store + fp32 residual
template <int EPI>
__global__ __launch_bounds__(256) void k_gemm(const unsigned short* __restrict__ A,
                                              const unsigned short* __restrict__ BT,
                                              int N, int K, int ldc,
                                              unsigned short* Cb,
                                              float* __restrict__ Cf,
                                              const float* __restrict__ Res) {
  __shared__ __align__(16) unsigned short at[128 * 32];
  __shared__ __align__(16) unsigned short bt[128 * 32];
  int t = threadIdx.x, w = t >> 6, l = t & 63;
  int g = l >> 4, c = l & 15;
  int wm = w >> 1, wn = w & 1;
  f32x4 acc[4][4] = {};
  const unsigned short* gA = A + (size_t)(blockIdx.y * 128 + (t >> 2)) * K + (t & 3) * 8;
  const unsigned short* gB = BT + (size_t)(blockIdx.x * 128 + (t >> 2)) * K + (t & 3) * 8;
  unsigned short* dA = &at[w * 512];  // wave-uniform base; HW adds lane*16B
  unsigned short* dB = &bt[w * 512];
  const int nk = K >> 5;
  for (int kt = 0; kt < nk; ++kt) {
    async16(dA, gA);
    async16(dA + 2048, gA + (size_t)64 * K);
    async16(dB, gB);
    async16(dB + 2048, gB + (size_t)64 * K);
    gA += 32; gB += 32;
    __syncthreads();
    s16x8 af[4], bfr[4];
#pragma unroll
    for (int m = 0; m < 4; ++m) af[m] = *(const s16x8*)&at[(wm * 64 + m * 16 + c) * 32 + g * 8];
#pragma unroll
    for (int n = 0; n < 4; ++n) bfr[n] = *(const s16x8*)&bt[(wn * 64 + n * 16 + c) * 32 + g * 8];
#pragma unroll
    for (int m = 0; m < 4; ++m)
#pragma unroll
      for (int n = 0; n < 4; ++n)
        acc[m][n] = mfma_bf16(af[m], bfr[n], acc[m][n]);
    __syncthreads();
  }
  size_t rb = (size_t)blockIdx.y * 128 + wm * 64;
  size_t cbase = (size_t)blockIdx.x * 128 + wn * 64;
#pragma unroll
  for (int m = 0; m < 4; ++m)
#pragma unroll
    for (int n = 0; n < 4; ++n)
#pragma unroll
      for (int r = 0; r < 4; ++r) {
        size_t row = rb + m * 16 + g * 4 + r;      // C row = (lane>>4)*4+reg
        size_t col = cbase + n * 16 + c;           // C col = lane&15
        float v = acc[m][n][r];
        if (EPI == 0) Cb[row * ldc + col] = f2bf(v);
        else Cf[row * ldc + col] = v + Res[row * ldc + col];
      }
}

// ---------- fused gate+up GEMM: inter = silu(A@Wg) * (A@Wu), BM=128 BN=64 ----------
__global__ __launch_bounds__(256) void k_gateup(const unsigned short* __restrict__ A,
                                                const unsigned short* __restrict__ BTg,
                                                const unsigned short* __restrict__ BTu,
                                                unsigned short* __restrict__ Cb) {
  __shared__ __align__(16) unsigned short at[128 * 32];
  __shared__ __align__(16) unsigned short bg[64 * 32];
  __shared__ __align__(16) unsigned short bu[64 * 32];
  int t = threadIdx.x, w = t >> 6, l = t & 63;
  int g = l >> 4, c = l & 15;
  int wm = w >> 1, wn = w & 1;
  f32x4 ag[4][2] = {}, au[4][2] = {};
  const unsigned short* gA = A + (size_t)(blockIdx.y * 128 + (t >> 2)) * 1024 + (t & 3) * 8;
  const unsigned short* gG = BTg + (size_t)(blockIdx.x * 64 + (t >> 2)) * 1024 + (t & 3) * 8;
  const unsigned short* gU = BTu + (size_t)(blockIdx.x * 64 + (t >> 2)) * 1024 + (t & 3) * 8;
  unsigned short* dA = &at[w * 512];
  unsigned short* dG = &bg[w * 512];
  unsigned short* dU = &bu[w * 512];
  for (int kt = 0; kt < 32; ++kt) {
    async16(dA, gA);
    async16(dA + 2048, gA + (size_t)64 * 1024);
    async16(dG, gG);
    async16(dU, gU);
    gA += 32; gG += 32; gU += 32;
    __syncthreads();
    s16x8 af[4], bgf[2], buf_[2];
#pragma unroll
    for (int m = 0; m < 4; ++m) af[m] = *(const s16x8*)&at[(wm * 64 + m * 16 + c) * 32 + g * 8];
#pragma unroll
    for (int n = 0; n < 2; ++n) {
      bgf[n] = *(const s16x8*)&bg[(wn * 32 + n * 16 + c) * 32 + g * 8];
      buf_[n] = *(const s16x8*)&bu[(wn * 32 + n * 16 + c) * 32 + g * 8];
    }
#pragma unroll
    for (int m = 0; m < 4; ++m)
#pragma unroll
      for (int n = 0; n < 2; ++n) {
        ag[m][n] = mfma_bf16(af[m], bgf[n], ag[m][n]);
        au[m][n] = mfma_bf16(af[m], buf_[n], au[m][n]);
      }
    __syncthreads();
  }
  size_t rb = (size_t)blockIdx.y * 128 + wm * 64;
  size_t cb = (size_t)blockIdx.x * 64 + wn * 32;
#pragma unroll
  for (int m = 0; m < 4; ++m)
#pragma unroll
    for (int n = 0; n < 2; ++n)
#pragma unroll
      for (int r = 0; r < 4; ++r) {
        size_t row = rb + m * 16 + g * 4 + r;
        size_t col = cb + n * 16 + c;
        float gv = ag[m][n][r], uv = au[m][n][r];
        Cb[row * 4096 + col] = f2bf(gv / (1.0f + __expf(-gv)) * uv);
      }
}

// ---------- Flash attention: 8 waves, dbuf swizzled tiles, log2-domain softmax ----------
// Swizzle: [64 rows][64 cols] bf16, 16B block index ^= (row&7) -> conflict-free b128.
// Softmax in log2 domain: S2 = QK*0.125*log2e + mask*log2e; P = 2^(S2 - m);
// defer-max (T13): skip alpha-rescale unless any row's max grew by > 8 (2^8 headroom in bf16).
__global__ __launch_bounds__(512) void k_attn(const unsigned short* __restrict__ Q,
                                              const unsigned short* __restrict__ K,
                                              const unsigned short* __restrict__ VT,
                                              const float* __restrict__ mask,
                                              unsigned short* __restrict__ Out) {
  __shared__ __align__(16) unsigned short Ks[2][64 * 64];
  __shared__ __align__(16) unsigned short VTs[2][64 * 64];
  __shared__ __align__(16) unsigned short Ps[8 * 16 * 68];
  const float LOG2E = 1.44269504f;
  const float SCL2 = 0.125f * 1.44269504f;
  int t = threadIdx.x, w = t >> 6, l = t & 63;
  int g = l >> 4, c = l & 15;
  int qw = w >> 2, hh = w & 3;           // qw 0..1 (16 q-rows), hh 0..3 (head in group)
  int blk = blockIdx.x;
  int qt = blk & 63, kvh = (blk >> 6) & 3, b = blk >> 8;
  size_t tokQ = (size_t)b * SS + qt * 32 + qw * 16;
  int head = kvh * 4 + hh;
  s16x8 qf[2];
#pragma unroll
  for (int st = 0; st < 2; ++st)
    qf[st] = *(const s16x8*)&Q[(tokQ + c) * 1536 + head * 64 + st * 32 + g * 8];

  // staging: 512 threads, each one 16B slot of K + one of VT
  int srow = t >> 3;
  int soff = srow * 64 + (((t & 7) ^ (srow & 7)) << 3);  // swizzled LDS short-offset
  const unsigned short* gK = K + ((size_t)b * SS + srow) * 1536 + kvh * 64 + (t & 7) * 8;
  const unsigned short* gV = VT + ((size_t)(b * 4 + kvh) * 64 + srow) * SS + (t & 7) * 8;

  int4 rK = *(const int4*)gK;            // tile 0
  int4 rV = *(const int4*)gV;
  *(int4*)&Ks[0][soff] = rK;
  *(int4*)&VTs[0][soff] = rV;

  const float* mrow = mask + (size_t)b * SS * SS + (size_t)(qt * 32 + qw * 16 + g * 4) * SS + c;
  float mcur[4][4], mnxt[4][4];
#pragma unroll
  for (int n = 0; n < 4; ++n)
#pragma unroll
    for (int r = 0; r < 4; ++r) mcur[n][r] = mrow[(size_t)r * SS + n * 16] * LOG2E;

  f32x4 aco[4] = {};
  float mrun[4], lrun[4];
#pragma unroll
  for (int r = 0; r < 4; ++r) { mrun[r] = -1e30f; lrun[r] = 0.f; }
  unsigned short* myP = &Ps[w * (16 * 68)];
  __syncthreads();

  for (int kt = 0; kt < 32; ++kt) {
    const unsigned short* Kc = Ks[kt & 1];
    const unsigned short* Vc = VTs[kt & 1];
    int nx = kt < 31 ? kt + 1 : 31;
    // prefetch next K/VT tile + next mask tile into registers
    rK = *(const int4*)(gK + (size_t)nx * 64 * 1536);
    rV = *(const int4*)(gV + nx * 64);
#pragma unroll
    for (int n = 0; n < 4; ++n)
#pragma unroll
      for (int r = 0; r < 4; ++r) mnxt[n][r] = mrow[(size_t)r * SS + nx * 64 + n * 16];

    // S = Q K^T   (rows q = g*4+r, cols k = n*16+c)
    f32x4 as[4] = {};
    __builtin_amdgcn_s_setprio(1);
#pragma unroll
    for (int st = 0; st < 2; ++st)
#pragma unroll
      for (int n = 0; n < 4; ++n) {
        s16x8 kb = *(const s16x8*)&Kc[(n * 16 + c) * 64 + (((st * 4 + g) ^ (c & 7)) << 3)];
        as[n] = mfma_bf16(qf[st], kb, as[n]);
      }
    __builtin_amdgcn_s_setprio(0);
    float sv[4][4];
#pragma unroll
    for (int n = 0; n < 4; ++n)
#pragma unroll
      for (int r = 0; r < 4; ++r) sv[n][r] = as[n][r] * SCL2 + mcur[n][r];
    // row max via DPP (row q = g*4+r lives in the aligned 16-lane group)
    float mx[4];
#pragma unroll
    for (int r = 0; r < 4; ++r) {
      float m0 = fmaxf(fmaxf(sv[0][r], sv[1][r]), fmaxf(sv[2][r], sv[3][r]));
      mx[r] = red16max(m0);
    }
    // defer-max: rescale only when some row's max grew past the 2^8 headroom
    float need = fmaxf(fmaxf(mx[0] - mrun[0], mx[1] - mrun[1]),
                       fmaxf(mx[2] - mrun[2], mx[3] - mrun[3]));
    if (__any(need > 8.0f)) {
#pragma unroll
      for (int r = 0; r < 4; ++r) {
        float mnew = fmaxf(mrun[r], mx[r]);
        float alpha = fexp2(mrun[r] - mnew);
        lrun[r] *= alpha;
#pragma unroll
        for (int n = 0; n < 4; ++n) aco[n][r] *= alpha;
        mrun[r] = mnew;
      }
    }
#pragma unroll
    for (int r = 0; r < 4; ++r) {
      float ps = 0.f;
#pragma unroll
      for (int n = 0; n < 4; ++n) {
        float p = fexp2(sv[n][r] - mrun[r]);
        ps += p;
        myP[(g * 4 + r) * 68 + n * 16 + c] = cvt1(p);  // stride 68 -> conflict-free
      }
      ps = red16sum(ps);
      lrun[r] += ps;
    }
    asm volatile("s_waitcnt lgkmcnt(0)" ::: "memory");  // P writes landed (wave-private slab)
    __builtin_amdgcn_sched_barrier(0);                  // rule #18: keep MFMA below the wait
    __builtin_amdgcn_s_setprio(1);
#pragma unroll
    for (int st = 0; st < 2; ++st) {
      s16x8 pa = *(const s16x8*)&myP[c * 68 + st * 32 + g * 8];
#pragma unroll
      for (int n = 0; n < 4; ++n) {
        s16x8 vb = *(const s16x8*)&Vc[(n * 16 + c) * 64 + (((st * 4 + g) ^ (c & 7)) << 3)];
        aco[n] = mfma_bf16(pa, vb, aco[n]);
      }
    }
    __builtin_amdgcn_s_setprio(0);
    if (kt < 31) {                       // write prefetched tile kt+1 to the other buffer
      *(int4*)&Ks[(kt + 1) & 1][soff] = rK;
      *(int4*)&VTs[(kt + 1) & 1][soff] = rV;
    }
#pragma unroll
    for (int n = 0; n < 4; ++n)
#pragma unroll
      for (int r = 0; r < 4; ++r) mcur[n][r] = mnxt[n][r] * LOG2E;
    __syncthreads();                     // single barrier per kt (dbuf)
  }
#pragma unroll
  for (int n = 0; n < 4; ++n)
#pragma unroll
    for (int r = 0; r < 4; ++r) {
      float v = aco[n][r] / lrun[r];
      Out[(tokQ + g * 4 + r) * 1024 + head * 64 + n * 16 + c] = f2bf(v);
    }
}

extern "C" void kernel_launch(void* const* d_in, const int* in_sizes, int n_in,
                              void* d_out, int out_size, void* d_ws, size_t ws_size,
                              hipStream_t stream) {
  (void)in_sizes; (void)n_in; (void)out_size; (void)ws_size;
  const float* hidden = (const float*)d_in[0];
  const float* kvst   = (const float*)d_in[1];
  const float* maskp  = (const float*)d_in[2];
  const float* ln1    = (const float*)d_in[3];
  const float* ln2    = (const float*)d_in[4];
  const float* Wq     = (const float*)d_in[5];
  const float* Wk     = (const float*)d_in[6];
  const float* Wv     = (const float*)d_in[7];
  const float* Wo     = (const float*)d_in[8];
  const float* Wg     = (const float*)d_in[9];
  const float* Wu     = (const float*)d_in[10];
  const float* Wd     = (const float*)d_in[11];
  float* out = (float*)d_out;

  char* ws = (char*)d_ws;
  size_t off = 0;
  auto alloc = [&](size_t bytes) { char* p = ws + off; off += (bytes + 255) & ~(size_t)255; return p; };
  unsigned short* WTqkv = (unsigned short*)alloc((size_t)1536 * 1024 * 2);
  unsigned short* WTo   = (unsigned short*)alloc((size_t)1024 * 1024 * 2);
  unsigned short* WTg   = (unsigned short*)alloc((size_t)4096 * 1024 * 2);
  unsigned short* WTu   = (unsigned short*)alloc((size_t)4096 * 1024 * 2);
  unsigned short* WTd   = (unsigned short*)alloc((size_t)1024 * 4096 * 2);
  float* cosT           = (float*)alloc((size_t)2048 * 32 * 4);
  float* sinT           = (float*)alloc((size_t)2048 * 32 * 4);
  unsigned short* hn    = (unsigned short*)alloc((size_t)4096 * 1024 * 2);
  unsigned short* kvn   = (unsigned short*)alloc((size_t)4096 * 1024 * 2);
  unsigned short* QKVb  = (unsigned short*)alloc((size_t)4096 * 1536 * 2);
  unsigned short* VTg   = (unsigned short*)alloc((size_t)8 * 64 * SS * 2);
  float* hid2           = (float*)alloc((size_t)4096 * 1024 * 4);
  unsigned short* inter = (unsigned short*)alloc((size_t)4096 * 4096 * 2);
  unsigned short* attnb = hn;   // hn dead after Q-proj
  unsigned short* h2n   = kvn;  // kvn dead after KV-proj

  // weights -> bf16 transposed (QKV packed: rows 0..1023 = Wq, 1024..1279 = Wk, 1280..1535 = Wv)
  k_transpose<<<dim3(32, 32), 256, 0, stream>>>(Wq, WTqkv, 1024, 1024);
  k_transpose<<<dim3(8, 32), 256, 0, stream>>>(Wk, WTqkv + (size_t)1024 * 1024, 1024, 256);
  k_transpose<<<dim3(8, 32), 256, 0, stream>>>(Wv, WTqkv + (size_t)1280 * 1024, 1024, 256);
  k_transpose<<<dim3(32, 32), 256, 0, stream>>>(Wo, WTo, 1024, 1024);
  k_transpose<<<dim3(128, 32), 256, 0, stream>>>(Wg, WTg, 1024, 4096);
  k_transpose<<<dim3(128, 32), 256, 0, stream>>>(Wu, WTu, 1024, 4096);
  k_transpose<<<dim3(32, 128), 256, 0, stream>>>(Wd, WTd, 4096, 1024);
  k_rope_tables<<<256, 256, 0, stream>>>(cosT, sinT);
  // norms
  k_rmsnorm<<<4096, 256, 0, stream>>>(hidden, ln1, hn);
  k_rmsnorm<<<4096, 256, 0, stream>>>(kvst, ln1, kvn);
  // projections into packed QKV [4096][1536]
  k_gemm<0><<<dim3(8, 32), 256, 0, stream>>>(hn, WTqkv, 1024, 1024, 1536, QKVb, nullptr, nullptr);
  k_gemm<0><<<dim3(4, 32), 256, 0, stream>>>(kvn, WTqkv + (size_t)1024 * 1024, 512, 1024, 1536,
                                             QKVb + 1024, nullptr, nullptr);
  // rope: heads 0..15 = Q, 16..19 = K (col h*64 in packed layout); V untouched
  k_rope<<<dim3(128, 20), 256, 0, stream>>>(QKVb, cosT, sinT, 1536);
  // V^T for conflict-free attention staging
  k_vtrans<<<dim3(64, 2, 8), 256, 0, stream>>>(QKVb, VTg);
  // attention
  k_attn<<<512, 512, 0, stream>>>(QKVb, QKVb + 1024, VTg, maskp, attnb);
  // O proj + residual
  k_gemm<1><<<dim3(8, 32), 256, 0, stream>>>(attnb, WTo, 1024, 1024, 1024, nullptr, hid2, hidden);
  // MLP
  k_rmsnorm<<<4096, 256, 0, stream>>>(hid2, ln2, h2n);
  k_gateup<<<dim3(64, 32), 256, 0, stream>>>(h2n, WTg, WTu, inter);
  k_gemm<1><<<dim3(8, 32), 256, 0, stream>>>(inter, WTd, 1024, 4096, 1024, nullptr, out, hid2);
}

// Round 6
// 374.966 us; speedup vs baseline: 1.3291x; 1.0703x over previous
//
#include <hip/hip_runtime.h>
#include <math.h>

#define SS 2048

typedef __attribute__((ext_vector_type(8))) short s16x8;
typedef __attribute__((ext_vector_type(4))) float f32x4;

__device__ __forceinline__ unsigned short f2bf(float f) {
  union { float f; unsigned u; } a; a.f = f;
  unsigned r = a.u + 0x7fffu + ((a.u >> 16) & 1u);   // RNE
  return (unsigned short)(r >> 16);
}
__device__ __forceinline__ float bf2f(unsigned short b) {
  union { unsigned u; float f; } a; a.u = ((unsigned)b) << 16;
  return a.f;
}
// single-instruction f32->bf16 (RNE) via v_cvt_pk_bf16_f32 (T12 recipe)
__device__ __forceinline__ unsigned short cvt1(float f) {
  unsigned v;
  asm("v_cvt_pk_bf16_f32 %0, %1, %1" : "=v"(v) : "v"(f));
  return (unsigned short)v;
}
// raw v_exp_f32 = 2^x (ISA: exp is base-2)
__device__ __forceinline__ float fexp2(float x) {
  float r; asm("v_exp_f32 %0, %1" : "=v"(r) : "v"(x)); return r;
}
__device__ __forceinline__ void async16(void* lds, const void* g) {
  __builtin_amdgcn_global_load_lds(
      (const __attribute__((address_space(1))) unsigned int*)g,
      (__attribute__((address_space(3))) unsigned int*)lds, 16, 0, 0);
}
__device__ __forceinline__ f32x4 mfma_bf16(s16x8 a, s16x8 b, f32x4 c) {
  return __builtin_amdgcn_mfma_f32_16x16x32_bf16(a, b, c, 0, 0, 0);
}

// DPP cross-lane within 16-lane rows (VALU pipe, no LDS latency).
template <int CTRL>
__device__ __forceinline__ float fdpp(float x) {
  union { float f; int i; } a; a.f = x;
  a.i = __builtin_amdgcn_update_dpp(0, a.i, CTRL, 0xF, 0xF, true);
  return a.f;
}
__device__ __forceinline__ float red16max(float x) {
  x = fmaxf(x, fdpp<0xB1>(x));
  x = fmaxf(x, fdpp<0x4E>(x));
  x = fmaxf(x, fdpp<0x141>(x));
  x = fmaxf(x, fdpp<0x140>(x));
  return x;
}
__device__ __forceinline__ float red16sum(float x) {
  x += fdpp<0xB1>(x);
  x += fdpp<0x4E>(x);
  x += fdpp<0x141>(x);
  x += fdpp<0x140>(x);
  return x;
}

// ---------- transpose + fp32->bf16: WT[n][k] = bf16(W[k][n]) ----------
__global__ __launch_bounds__(256) void k_transpose(const float* __restrict__ W,
                                                   unsigned short* __restrict__ WT,
                                                   int K, int N) {
  __shared__ float tile[32][33];
  int t = threadIdx.x;
  int tx = t & 31, ty = t >> 5;
  int n0 = blockIdx.x * 32, k0 = blockIdx.y * 32;
#pragma unroll
  for (int i = 0; i < 4; ++i)
    tile[ty + 8 * i][tx] = W[(size_t)(k0 + ty + 8 * i) * N + n0 + tx];
  __syncthreads();
#pragma unroll
  for (int i = 0; i < 4; ++i)
    WT[(size_t)(n0 + ty + 8 * i) * K + k0 + tx] = f2bf(tile[tx][ty + 8 * i]);
}

// ---------- V^T precompute: VT[(b*4+kvh)][d=64][s=2048] from QKV cols 1280.. ----------
__global__ __launch_bounds__(256) void k_vtrans(const unsigned short* __restrict__ QKV,
                                                unsigned short* __restrict__ VT) {
  __shared__ unsigned short tile[32][33];
  int t = threadIdx.x, tx = t & 31, ty = t >> 5;
  int s0 = blockIdx.x * 32, d0 = blockIdx.y * 32;
  int bk = blockIdx.z; int b = bk >> 2, kvh = bk & 3;
#pragma unroll
  for (int i = 0; i < 4; ++i)
    tile[ty + 8 * i][tx] =
        QKV[((size_t)b * SS + s0 + ty + 8 * i) * 1536 + 1280 + kvh * 64 + d0 + tx];
  __syncthreads();
#pragma unroll
  for (int i = 0; i < 4; ++i)
    VT[((size_t)bk * 64 + d0 + ty + 8 * i) * SS + s0 + tx] = tile[tx][ty + 8 * i];
}

// ---------- RoPE tables (double precision, once per launch) ----------
__global__ void k_rope_tables(float* __restrict__ cosT, float* __restrict__ sinT) {
  int idx = blockIdx.x * 256 + threadIdx.x;  // 65536 = 2048*32
  int s = idx >> 5, i = idx & 31;
  double ang = (double)s * pow(10000.0, -(double)(2 * i) / 64.0);
  cosT[idx] = (float)cos(ang);
  sinT[idx] = (float)sin(ang);
}

// ---------- RMSNorm fp32 -> bf16 (one block per row, H=1024) ----------
__global__ __launch_bounds__(256) void k_rmsnorm(const float* __restrict__ X,
                                                 const float* __restrict__ Wt,
                                                 unsigned short* __restrict__ Y) {
  int row = blockIdx.x, t = threadIdx.x;
  float4 v = ((const float4*)X)[(size_t)row * 256 + t];
  float ssq = v.x * v.x + v.y * v.y + v.z * v.z + v.w * v.w;
#pragma unroll
  for (int m = 1; m < 64; m <<= 1) ssq += __shfl_xor(ssq, m);
  __shared__ float red[4];
  if ((t & 63) == 0) red[t >> 6] = ssq;
  __syncthreads();
  float sc = rsqrtf((red[0] + red[1] + red[2] + red[3]) * (1.0f / 1024.0f) + 1e-6f);
  float4 wv = ((const float4*)Wt)[t];
  ushort4 o;
  o.x = f2bf(v.x * sc * wv.x); o.y = f2bf(v.y * sc * wv.y);
  o.z = f2bf(v.z * sc * wv.z); o.w = f2bf(v.w * sc * wv.w);
  ((ushort4*)Y)[(size_t)row * 256 + t] = o;
}

// ---------- RoPE in place on QKV buffer; head = blockIdx.y ----------
__global__ __launch_bounds__(256) void k_rope(unsigned short* __restrict__ X,
                                              const float* __restrict__ cosT,
                                              const float* __restrict__ sinT,
                                              int stride) {
  int idx = blockIdx.x * 256 + threadIdx.x;  // tok*8+seg, tok 0..4095
  int seg = idx & 7, tok = idx >> 3;
  int head = blockIdx.y;
  int s = tok & (SS - 1);
  int d0 = seg * 4;
  unsigned short* p = X + (size_t)tok * stride + head * 64;
  ushort4 lo = *(ushort4*)&p[d0];
  ushort4 hi = *(ushort4*)&p[d0 + 32];
  float4 cs = *(const float4*)&cosT[s * 32 + d0];
  float4 sn = *(const float4*)&sinT[s * 32 + d0];
  ushort4 olo, ohi;
  olo.x = f2bf(bf2f(lo.x) * cs.x - bf2f(hi.x) * sn.x);
  olo.y = f2bf(bf2f(lo.y) * cs.y - bf2f(hi.y) * sn.y);
  olo.z = f2bf(bf2f(lo.z) * cs.z - bf2f(hi.z) * sn.z);
  olo.w = f2bf(bf2f(lo.w) * cs.w - bf2f(hi.w) * sn.w);
  ohi.x = f2bf(bf2f(hi.x) * cs.x + bf2f(lo.x) * sn.x);
  ohi.y = f2bf(bf2f(hi.y) * cs.y + bf2f(lo.y) * sn.y);
  ohi.z = f2bf(bf2f(hi.z) * cs.z + bf2f(lo.z) * sn.z);
  ohi.w = f2bf(bf2f(hi.w) * cs.w + bf2f(lo.w) * sn.w);
  *(ushort4*)&p[d0] = olo;
  *(ushort4*)&p[d0 + 32] = ohi;
}

// ---------- GEMM: C[M,N] = A[M,K](bf16) x BT[N,K](bf16), m97 structure ----------
// BM=128 fixed; BN template (64 doubles grid for small-N shapes -> 2 blocks/CU).
// EPI: 0 = bf16 store, 1 = fp32 store + fp32 residual
template <int EPI, int BN>
__global__ __launch_bounds__(256) void k_gemm(const unsigned short* __restrict__ A,
                                              const unsigned short* __restrict__ BT,
                                              int K, int ldc,
                                              unsigned short* Cb,
                                              float* __restrict__ Cf,
                                              const float* __restrict__ Res) {
  constexpr int NW = BN / 32;                 // wave N-subtiles
  __shared__ __align__(16) unsigned short at[128 * 32];
  __shared__ __align__(16) unsigned short bt[BN * 32];
  int t = threadIdx.x, w = t >> 6, l = t & 63;
  int g = l >> 4, c = l & 15;
  int wm = w >> 1, wn = w & 1;
  f32x4 acc[4][NW] = {};
  const unsigned short* gA = A + (size_t)(blockIdx.y * 128 + (t >> 2)) * K + (t & 3) * 8;
  const unsigned short* gB = BT + (size_t)(blockIdx.x * BN + (t >> 2)) * K + (t & 3) * 8;
  unsigned short* dA = &at[w * 512];  // wave-uniform base; HW adds lane*16B
  unsigned short* dB = &bt[w * 512];
  const int nk = K >> 5;
  for (int kt = 0; kt < nk; ++kt) {
    async16(dA, gA);
    async16(dA + 2048, gA + (size_t)64 * K);
    async16(dB, gB);
    if (BN == 128) async16(dB + 2048, gB + (size_t)64 * K);
    gA += 32; gB += 32;
    __syncthreads();
    s16x8 af[4], bfr[NW];
#pragma unroll
    for (int m = 0; m < 4; ++m) af[m] = *(const s16x8*)&at[(wm * 64 + m * 16 + c) * 32 + g * 8];
#pragma unroll
    for (int n = 0; n < NW; ++n)
      bfr[n] = *(const s16x8*)&bt[(wn * (BN / 2) + n * 16 + c) * 32 + g * 8];
#pragma unroll
    for (int m = 0; m < 4; ++m)
#pragma unroll
      for (int n = 0; n < NW; ++n)
        acc[m][n] = mfma_bf16(af[m], bfr[n], acc[m][n]);
    __syncthreads();
  }
  size_t rb = (size_t)blockIdx.y * 128 + wm * 64;
  size_t cbase = (size_t)blockIdx.x * BN + wn * (BN / 2);
#pragma unroll
  for (int m = 0; m < 4; ++m)
#pragma unroll
    for (int n = 0; n < NW; ++n)
#pragma unroll
      for (int r = 0; r < 4; ++r) {
        size_t row = rb + m * 16 + g * 4 + r;      // C row = (lane>>4)*4+reg
        size_t col = cbase + n * 16 + c;           // C col = lane&15
        float v = acc[m][n][r];
        if (EPI == 0) Cb[row * ldc + col] = f2bf(v);
        else Cf[row * ldc + col] = v + Res[row * ldc + col];
      }
}

// ---------- fused gate+up GEMM: inter = silu(A@Wg) * (A@Wu), BM=128 BN=64 ----------
__global__ __launch_bounds__(256) void k_gateup(const unsigned short* __restrict__ A,
                                                const unsigned short* __restrict__ BTg,
                                                const unsigned short* __restrict__ BTu,
                                                unsigned short* __restrict__ Cb) {
  __shared__ __align__(16) unsigned short at[128 * 32];
  __shared__ __align__(16) unsigned short bg[64 * 32];
  __shared__ __align__(16) unsigned short bu[64 * 32];
  int t = threadIdx.x, w = t >> 6, l = t & 63;
  int g = l >> 4, c = l & 15;
  int wm = w >> 1, wn = w & 1;
  f32x4 ag[4][2] = {}, au[4][2] = {};
  const unsigned short* gA = A + (size_t)(blockIdx.y * 128 + (t >> 2)) * 1024 + (t & 3) * 8;
  const unsigned short* gG = BTg + (size_t)(blockIdx.x * 64 + (t >> 2)) * 1024 + (t & 3) * 8;
  const unsigned short* gU = BTu + (size_t)(blockIdx.x * 64 + (t >> 2)) * 1024 + (t & 3) * 8;
  unsigned short* dA = &at[w * 512];
  unsigned short* dG = &bg[w * 512];
  unsigned short* dU = &bu[w * 512];
  for (int kt = 0; kt < 32; ++kt) {
    async16(dA, gA);
    async16(dA + 2048, gA + (size_t)64 * 1024);
    async16(dG, gG);
    async16(dU, gU);
    gA += 32; gG += 32; gU += 32;
    __syncthreads();
    s16x8 af[4], bgf[2], buf_[2];
#pragma unroll
    for (int m = 0; m < 4; ++m) af[m] = *(const s16x8*)&at[(wm * 64 + m * 16 + c) * 32 + g * 8];
#pragma unroll
    for (int n = 0; n < 2; ++n) {
      bgf[n] = *(const s16x8*)&bg[(wn * 32 + n * 16 + c) * 32 + g * 8];
      buf_[n] = *(const s16x8*)&bu[(wn * 32 + n * 16 + c) * 32 + g * 8];
    }
#pragma unroll
    for (int m = 0; m < 4; ++m)
#pragma unroll
      for (int n = 0; n < 2; ++n) {
        ag[m][n] = mfma_bf16(af[m], bgf[n], ag[m][n]);
        au[m][n] = mfma_bf16(af[m], buf_[n], au[m][n]);
      }
    __syncthreads();
  }
  size_t rb = (size_t)blockIdx.y * 128 + wm * 64;
  size_t cb = (size_t)blockIdx.x * 64 + wn * 32;
#pragma unroll
  for (int m = 0; m < 4; ++m)
#pragma unroll
    for (int n = 0; n < 2; ++n)
#pragma unroll
      for (int r = 0; r < 4; ++r) {
        size_t row = rb + m * 16 + g * 4 + r;
        size_t col = cb + n * 16 + c;
        float gv = ag[m][n][r], uv = au[m][n][r];
        Cb[row * 4096 + col] = f2bf(gv / (1.0f + __expf(-gv)) * uv);
      }
}

// ---------- Flash attention, KV-split x2 (flash-decoding): grid 1024, 8 waves ----------
// Each block does half the KV range (1024 tokens, 16 tiles) and writes UNNORMALIZED
// O-partials (f32) + per-row (m, l) in log2 domain. k_comb merges the two halves.
__global__ __launch_bounds__(512) void k_attn(const unsigned short* __restrict__ Q,
                                              const unsigned short* __restrict__ K,
                                              const unsigned short* __restrict__ VT,
                                              const float* __restrict__ mask,
                                              float* __restrict__ Opart,
                                              float2* __restrict__ Ml) {
  __shared__ __align__(16) unsigned short Ks[2][64 * 64];
  __shared__ __align__(16) unsigned short VTs[2][64 * 64];
  __shared__ __align__(16) unsigned short Ps[8 * 16 * 68];
  const float LOG2E = 1.44269504f;
  const float SCL2 = 0.125f * 1.44269504f;
  int t = threadIdx.x, w = t >> 6, l = t & 63;
  int g = l >> 4, c = l & 15;
  int qw = w >> 2, hh = w & 3;           // qw 0..1 (16 q-rows), hh 0..3 (head in group)
  int blk = blockIdx.x;
  int half = blk & 1, qt = (blk >> 1) & 63, kvh = (blk >> 7) & 3, b = blk >> 9;
  size_t tokQ = (size_t)b * SS + qt * 32 + qw * 16;
  int head = kvh * 4 + hh;
  s16x8 qf[2];
#pragma unroll
  for (int st = 0; st < 2; ++st)
    qf[st] = *(const s16x8*)&Q[(tokQ + c) * 1536 + head * 64 + st * 32 + g * 8];

  // staging: 512 threads, each one 16B slot of K + one of VT
  int srow = t >> 3;
  int soff = srow * 64 + (((t & 7) ^ (srow & 7)) << 3);  // swizzled LDS short-offset
  const unsigned short* gK =
      K + ((size_t)b * SS + half * 1024 + srow) * 1536 + kvh * 64 + (t & 7) * 8;
  const unsigned short* gV =
      VT + ((size_t)(b * 4 + kvh) * 64 + srow) * SS + half * 1024 + (t & 7) * 8;

  int4 rK = *(const int4*)gK;            // tile 0
  int4 rV = *(const int4*)gV;
  *(int4*)&Ks[0][soff] = rK;
  *(int4*)&VTs[0][soff] = rV;

  const float* mrow = mask + (size_t)b * SS * SS +
                      (size_t)(qt * 32 + qw * 16 + g * 4) * SS + half * 1024 + c;
  float mcur[4][4], mnxt[4][4];
#pragma unroll
  for (int n = 0; n < 4; ++n)
#pragma unroll
    for (int r = 0; r < 4; ++r) mcur[n][r] = mrow[(size_t)r * SS + n * 16] * LOG2E;

  f32x4 aco[4] = {};
  float mrun[4], lrun[4];
#pragma unroll
  for (int r = 0; r < 4; ++r) { mrun[r] = -1e30f; lrun[r] = 0.f; }
  unsigned short* myP = &Ps[w * (16 * 68)];
  __syncthreads();

  for (int kt = 0; kt < 16; ++kt) {
    const unsigned short* Kc = Ks[kt & 1];
    const unsigned short* Vc = VTs[kt & 1];
    int nx = kt < 15 ? kt + 1 : 15;
    // prefetch next K/VT tile + next mask tile into registers
    rK = *(const int4*)(gK + (size_t)nx * 64 * 1536);
    rV = *(const int4*)(gV + nx * 64);
#pragma unroll
    for (int n = 0; n < 4; ++n)
#pragma unroll
      for (int r = 0; r < 4; ++r) mnxt[n][r] = mrow[(size_t)r * SS + nx * 64 + n * 16];

    // S = Q K^T   (rows q = g*4+r, cols k = n*16+c)
    f32x4 as[4] = {};
    __builtin_amdgcn_s_setprio(1);
#pragma unroll
    for (int st = 0; st < 2; ++st)
#pragma unroll
      for (int n = 0; n < 4; ++n) {
        s16x8 kb = *(const s16x8*)&Kc[(n * 16 + c) * 64 + (((st * 4 + g) ^ (c & 7)) << 3)];
        as[n] = mfma_bf16(qf[st], kb, as[n]);
      }
    __builtin_amdgcn_s_setprio(0);
    float sv[4][4];
#pragma unroll
    for (int n = 0; n < 4; ++n)
#pragma unroll
      for (int r = 0; r < 4; ++r) sv[n][r] = as[n][r] * SCL2 + mcur[n][r];
    // row max via DPP (row q = g*4+r lives in the aligned 16-lane group)
    float mx[4];
#pragma unroll
    for (int r = 0; r < 4; ++r) {
      float m0 = fmaxf(fmaxf(sv[0][r], sv[1][r]), fmaxf(sv[2][r], sv[3][r]));
      mx[r] = red16max(m0);
    }
    // defer-max: rescale only when some row's max grew past the 2^8 headroom
    float need = fmaxf(fmaxf(mx[0] - mrun[0], mx[1] - mrun[1]),
                       fmaxf(mx[2] - mrun[2], mx[3] - mrun[3]));
    if (__any(need > 8.0f)) {
#pragma unroll
      for (int r = 0; r < 4; ++r) {
        float mnew = fmaxf(mrun[r], mx[r]);
        float alpha = fexp2(mrun[r] - mnew);
        lrun[r] *= alpha;
#pragma unroll
        for (int n = 0; n < 4; ++n) aco[n][r] *= alpha;
        mrun[r] = mnew;
      }
    }
#pragma unroll
    for (int r = 0; r < 4; ++r) {
      float ps = 0.f;
#pragma unroll
      for (int n = 0; n < 4; ++n) {
        float p = fexp2(sv[n][r] - mrun[r]);
        ps += p;
        myP[(g * 4 + r) * 68 + n * 16 + c] = cvt1(p);  // stride 68 -> conflict-free
      }
      ps = red16sum(ps);
      lrun[r] += ps;
    }
    asm volatile("s_waitcnt lgkmcnt(0)" ::: "memory");  // P writes landed (wave-private slab)
    __builtin_amdgcn_sched_barrier(0);                  // rule #18: keep MFMA below the wait
    __builtin_amdgcn_s_setprio(1);
#pragma unroll
    for (int st = 0; st < 2; ++st) {
      s16x8 pa = *(const s16x8*)&myP[c * 68 + st * 32 + g * 8];
#pragma unroll
      for (int n = 0; n < 4; ++n) {
        s16x8 vb = *(const s16x8*)&Vc[(n * 16 + c) * 64 + (((st * 4 + g) ^ (c & 7)) << 3)];
        aco[n] = mfma_bf16(pa, vb, aco[n]);
      }
    }
    __builtin_amdgcn_s_setprio(0);
    if (kt < 15) {                       // write prefetched tile kt+1 to the other buffer
      *(int4*)&Ks[(kt + 1) & 1][soff] = rK;
      *(int4*)&VTs[(kt + 1) & 1][soff] = rV;
    }
#pragma unroll
    for (int n = 0; n < 4; ++n)
#pragma unroll
      for (int r = 0; r < 4; ++r) mcur[n][r] = mnxt[n][r] * LOG2E;
    __syncthreads();                     // single barrier per kt (dbuf)
  }
  // store UNNORMALIZED partials + (m, l)
#pragma unroll
  for (int n = 0; n < 4; ++n)
#pragma unroll
    for (int r = 0; r < 4; ++r)
      Opart[((size_t)half * 4096 + tokQ + g * 4 + r) * 1024 + head * 64 + n * 16 + c] =
          aco[n][r];
  if (c == 0) {
#pragma unroll
    for (int r = 0; r < 4; ++r) {
      float2 v; v.x = mrun[r]; v.y = lrun[r];
      Ml[((size_t)half * 4096 + tokQ + g * 4 + r) * 16 + head] = v;
    }
  }
}

// ---------- combine the two KV halves: out = (O0*a0 + O1*a1) / (l0*a0 + l1*a1) ----------
__global__ __launch_bounds__(256) void k_comb(const float* __restrict__ Opart,
                                              const float2* __restrict__ Ml,
                                              unsigned short* __restrict__ Out) {
  int tok = blockIdx.x, t = threadIdx.x;
  int col = t * 4, head = col >> 6;
  float2 h0 = Ml[(size_t)tok * 16 + head];
  float2 h1 = Ml[(size_t)(4096 + tok) * 16 + head];
  float M = fmaxf(h0.x, h1.x);
  float a0 = fexp2(h0.x - M), a1 = fexp2(h1.x - M);
  float inv = 1.0f / (h0.y * a0 + h1.y * a1);
  float4 O0 = *(const float4*)&Opart[(size_t)tok * 1024 + col];
  float4 O1 = *(const float4*)&Opart[(size_t)(4096 + tok) * 1024 + col];
  ushort4 o;
  o.x = f2bf((O0.x * a0 + O1.x * a1) * inv);
  o.y = f2bf((O0.y * a0 + O1.y * a1) * inv);
  o.z = f2bf((O0.z * a0 + O1.z * a1) * inv);
  o.w = f2bf((O0.w * a0 + O1.w * a1) * inv);
  *(ushort4*)&Out[(size_t)tok * 1024 + col] = o;
}

extern "C" void kernel_launch(void* const* d_in, const int* in_sizes, int n_in,
                              void* d_out, int out_size, void* d_ws, size_t ws_size,
                              hipStream_t stream) {
  (void)in_sizes; (void)n_in; (void)out_size; (void)ws_size;
  const float* hidden = (const float*)d_in[0];
  const float* kvst   = (const float*)d_in[1];
  const float* maskp  = (const float*)d_in[2];
  const float* ln1    = (const float*)d_in[3];
  const float* ln2    = (const float*)d_in[4];
  const float* Wq     = (const float*)d_in[5];
  const float* Wk     = (const float*)d_in[6];
  const float* Wv     = (const float*)d_in[7];
  const float* Wo     = (const float*)d_in[8];
  const float* Wg     = (const float*)d_in[9];
  const float* Wu     = (const float*)d_in[10];
  const float* Wd     = (const float*)d_in[11];
  float* out = (float*)d_out;

  char* ws = (char*)d_ws;
  size_t off = 0;
  auto alloc = [&](size_t bytes) { char* p = ws + off; off += (bytes + 255) & ~(size_t)255; return p; };
  unsigned short* WTqkv = (unsigned short*)alloc((size_t)1536 * 1024 * 2);
  unsigned short* WTo   = (unsigned short*)alloc((size_t)1024 * 1024 * 2);
  unsigned short* WTg   = (unsigned short*)alloc((size_t)4096 * 1024 * 2);
  unsigned short* WTu   = (unsigned short*)alloc((size_t)4096 * 1024 * 2);
  unsigned short* WTd   = (unsigned short*)alloc((size_t)1024 * 4096 * 2);
  float* cosT           = (float*)alloc((size_t)2048 * 32 * 4);
  float* sinT           = (float*)alloc((size_t)2048 * 32 * 4);
  unsigned short* hn    = (unsigned short*)alloc((size_t)4096 * 1024 * 2);
  unsigned short* kvn   = (unsigned short*)alloc((size_t)4096 * 1024 * 2);
  unsigned short* QKVb  = (unsigned short*)alloc((size_t)4096 * 1536 * 2);
  unsigned short* VTg   = (unsigned short*)alloc((size_t)8 * 64 * SS * 2);
  float* hid2           = (float*)alloc((size_t)4096 * 1024 * 4);
  unsigned short* inter = (unsigned short*)alloc((size_t)4096 * 4096 * 2);
  unsigned short* attnb = hn;              // hn dead after Q-proj
  unsigned short* h2n   = kvn;             // kvn dead after KV-proj
  float* Opart          = (float*)inter;   // 32MB; inter written later by gateup
  float2* Ml            = (float2*)hid2;   // 1MB; hid2 written later by O-proj

  // weights -> bf16 transposed (QKV packed: rows 0..1023 = Wq, 1024..1279 = Wk, 1280..1535 = Wv)
  k_transpose<<<dim3(32, 32), 256, 0, stream>>>(Wq, WTqkv, 1024, 1024);
  k_transpose<<<dim3(8, 32), 256, 0, stream>>>(Wk, WTqkv + (size_t)1024 * 1024, 1024, 256);
  k_transpose<<<dim3(8, 32), 256, 0, stream>>>(Wv, WTqkv + (size_t)1280 * 1024, 1024, 256);
  k_transpose<<<dim3(32, 32), 256, 0, stream>>>(Wo, WTo, 1024, 1024);
  k_transpose<<<dim3(128, 32), 256, 0, stream>>>(Wg, WTg, 1024, 4096);
  k_transpose<<<dim3(128, 32), 256, 0, stream>>>(Wu, WTu, 1024, 4096);
  k_transpose<<<dim3(32, 128), 256, 0, stream>>>(Wd, WTd, 4096, 1024);
  k_rope_tables<<<256, 256, 0, stream>>>(cosT, sinT);
  // norms
  k_rmsnorm<<<4096, 256, 0, stream>>>(hidden, ln1, hn);
  k_rmsnorm<<<4096, 256, 0, stream>>>(kvst, ln1, kvn);
  // projections into packed QKV [4096][1536]  (BN=64 -> 2 blocks/CU)
  k_gemm<0, 64><<<dim3(16, 32), 256, 0, stream>>>(hn, WTqkv, 1024, 1536, QKVb, nullptr, nullptr);
  k_gemm<0, 64><<<dim3(8, 32), 256, 0, stream>>>(kvn, WTqkv + (size_t)1024 * 1024, 1024, 1536,
                                                 QKVb + 1024, nullptr, nullptr);
  // rope: heads 0..15 = Q, 16..19 = K (col h*64 in packed layout); V untouched
  k_rope<<<dim3(128, 20), 256, 0, stream>>>(QKVb, cosT, sinT, 1536);
  // V^T for conflict-free attention staging
  k_vtrans<<<dim3(64, 2, 8), 256, 0, stream>>>(QKVb, VTg);
  // attention (KV-split x2) + combine
  k_attn<<<1024, 512, 0, stream>>>(QKVb, QKVb + 1024, VTg, maskp, Opart, Ml);
  k_comb<<<4096, 256, 0, stream>>>(Opart, Ml, attnb);
  // O proj + residual
  k_gemm<1, 64><<<dim3(16, 32), 256, 0, stream>>>(attnb, WTo, 1024, 1024, nullptr, hid2, hidden);
  // MLP
  k_rmsnorm<<<4096, 256, 0, stream>>>(hid2, ln2, h2n);
  k_gateup<<<dim3(64, 32), 256, 0, stream>>>(h2n, WTg, WTu, inter);
  k_gemm<1, 64><<<dim3(16, 32), 256, 0, stream>>>(inter, WTd, 4096, 1024, nullptr, out, hid2);
}

// Round 7
// 360.075 us; speedup vs baseline: 1.3841x; 1.0414x over previous
//
#include <hip/hip_runtime.h>
#include <math.h>

#define SS 2048

typedef __attribute__((ext_vector_type(8))) short s16x8;
typedef __attribute__((ext_vector_type(4))) float f32x4;

__device__ __forceinline__ unsigned short f2bf(float f) {
  union { float f; unsigned u; } a; a.f = f;
  unsigned r = a.u + 0x7fffu + ((a.u >> 16) & 1u);   // RNE
  return (unsigned short)(r >> 16);
}
__device__ __forceinline__ float bf2f(unsigned short b) {
  union { unsigned u; float f; } a; a.u = ((unsigned)b) << 16;
  return a.f;
}
// single-instruction f32->bf16 (RNE) via v_cvt_pk_bf16_f32 (T12 recipe)
__device__ __forceinline__ unsigned short cvt1(float f) {
  unsigned v;
  asm("v_cvt_pk_bf16_f32 %0, %1, %1" : "=v"(v) : "v"(f));
  return (unsigned short)v;
}
// raw v_exp_f32 = 2^x (ISA: exp is base-2)
__device__ __forceinline__ float fexp2(float x) {
  float r; asm("v_exp_f32 %0, %1" : "=v"(r) : "v"(x)); return r;
}
__device__ __forceinline__ void async16(void* lds, const void* g) {
  __builtin_amdgcn_global_load_lds(
      (const __attribute__((address_space(1))) unsigned int*)g,
      (__attribute__((address_space(3))) unsigned int*)lds, 16, 0, 0);
}
__device__ __forceinline__ f32x4 mfma_bf16(s16x8 a, s16x8 b, f32x4 c) {
  return __builtin_amdgcn_mfma_f32_16x16x32_bf16(a, b, c, 0, 0, 0);
}

// DPP cross-lane within 16-lane rows (VALU pipe, no LDS latency).
template <int CTRL>
__device__ __forceinline__ float fdpp(float x) {
  union { float f; int i; } a; a.f = x;
  a.i = __builtin_amdgcn_update_dpp(0, a.i, CTRL, 0xF, 0xF, true);
  return a.f;
}
__device__ __forceinline__ float red16max(float x) {
  x = fmaxf(x, fdpp<0xB1>(x));
  x = fmaxf(x, fdpp<0x4E>(x));
  x = fmaxf(x, fdpp<0x141>(x));
  x = fmaxf(x, fdpp<0x140>(x));
  return x;
}

// ---------- transpose + fp32->bf16: WT[n][k] = bf16(W[k][n]) ----------
__global__ __launch_bounds__(256) void k_transpose(const float* __restrict__ W,
                                                   unsigned short* __restrict__ WT,
                                                   int K, int N) {
  __shared__ float tile[32][33];
  int t = threadIdx.x;
  int tx = t & 31, ty = t >> 5;
  int n0 = blockIdx.x * 32, k0 = blockIdx.y * 32;
#pragma unroll
  for (int i = 0; i < 4; ++i)
    tile[ty + 8 * i][tx] = W[(size_t)(k0 + ty + 8 * i) * N + n0 + tx];
  __syncthreads();
#pragma unroll
  for (int i = 0; i < 4; ++i)
    WT[(size_t)(n0 + ty + 8 * i) * K + k0 + tx] = f2bf(tile[tx][ty + 8 * i]);
}

// ---------- V^T precompute: VT[(b*4+kvh)][d=64][s=2048] from QKV cols 1280.. ----------
__global__ __launch_bounds__(256) void k_vtrans(const unsigned short* __restrict__ QKV,
                                                unsigned short* __restrict__ VT) {
  __shared__ unsigned short tile[32][33];
  int t = threadIdx.x, tx = t & 31, ty = t >> 5;
  int s0 = blockIdx.x * 32, d0 = blockIdx.y * 32;
  int bk = blockIdx.z; int b = bk >> 2, kvh = bk & 3;
#pragma unroll
  for (int i = 0; i < 4; ++i)
    tile[ty + 8 * i][tx] =
        QKV[((size_t)b * SS + s0 + ty + 8 * i) * 1536 + 1280 + kvh * 64 + d0 + tx];
  __syncthreads();
#pragma unroll
  for (int i = 0; i < 4; ++i)
    VT[((size_t)bk * 64 + d0 + ty + 8 * i) * SS + s0 + tx] = tile[tx][ty + 8 * i];
}

// ---------- RoPE tables (double precision, once per launch) ----------
__global__ void k_rope_tables(float* __restrict__ cosT, float* __restrict__ sinT) {
  int idx = blockIdx.x * 256 + threadIdx.x;  // 65536 = 2048*32
  int s = idx >> 5, i = idx & 31;
  double ang = (double)s * pow(10000.0, -(double)(2 * i) / 64.0);
  cosT[idx] = (float)cos(ang);
  sinT[idx] = (float)sin(ang);
}

// ---------- RMSNorm fp32 -> bf16 (one block per row, H=1024) ----------
__global__ __launch_bounds__(256) void k_rmsnorm(const float* __restrict__ X,
                                                 const float* __restrict__ Wt,
                                                 unsigned short* __restrict__ Y) {
  int row = blockIdx.x, t = threadIdx.x;
  float4 v = ((const float4*)X)[(size_t)row * 256 + t];
  float ssq = v.x * v.x + v.y * v.y + v.z * v.z + v.w * v.w;
#pragma unroll
  for (int m = 1; m < 64; m <<= 1) ssq += __shfl_xor(ssq, m);
  __shared__ float red[4];
  if ((t & 63) == 0) red[t >> 6] = ssq;
  __syncthreads();
  float sc = rsqrtf((red[0] + red[1] + red[2] + red[3]) * (1.0f / 1024.0f) + 1e-6f);
  float4 wv = ((const float4*)Wt)[t];
  ushort4 o;
  o.x = f2bf(v.x * sc * wv.x); o.y = f2bf(v.y * sc * wv.y);
  o.z = f2bf(v.z * sc * wv.z); o.w = f2bf(v.w * sc * wv.w);
  ((ushort4*)Y)[(size_t)row * 256 + t] = o;
}

// ---------- RoPE in place on QKV buffer; head = blockIdx.y ----------
__global__ __launch_bounds__(256) void k_rope(unsigned short* __restrict__ X,
                                              const float* __restrict__ cosT,
                                              const float* __restrict__ sinT,
                                              int stride) {
  int idx = blockIdx.x * 256 + threadIdx.x;  // tok*8+seg, tok 0..4095
  int seg = idx & 7, tok = idx >> 3;
  int head = blockIdx.y;
  int s = tok & (SS - 1);
  int d0 = seg * 4;
  unsigned short* p = X + (size_t)tok * stride + head * 64;
  ushort4 lo = *(ushort4*)&p[d0];
  ushort4 hi = *(ushort4*)&p[d0 + 32];
  float4 cs = *(const float4*)&cosT[s * 32 + d0];
  float4 sn = *(const float4*)&sinT[s * 32 + d0];
  ushort4 olo, ohi;
  olo.x = f2bf(bf2f(lo.x) * cs.x - bf2f(hi.x) * sn.x);
  olo.y = f2bf(bf2f(lo.y) * cs.y - bf2f(hi.y) * sn.y);
  olo.z = f2bf(bf2f(lo.z) * cs.z - bf2f(hi.z) * sn.z);
  olo.w = f2bf(bf2f(lo.w) * cs.w - bf2f(hi.w) * sn.w);
  ohi.x = f2bf(bf2f(hi.x) * cs.x + bf2f(lo.x) * sn.x);
  ohi.y = f2bf(bf2f(hi.y) * cs.y + bf2f(lo.y) * sn.y);
  ohi.z = f2bf(bf2f(hi.z) * cs.z + bf2f(lo.z) * sn.z);
  ohi.w = f2bf(bf2f(hi.w) * cs.w + bf2f(lo.w) * sn.w);
  *(ushort4*)&p[d0] = olo;
  *(ushort4*)&p[d0 + 32] = ohi;
}

// ---------- GEMM: C[M,N] = A[M,K](bf16) x BT[N,K](bf16), m97 structure ----------
// BM=128 fixed; BN template (64 doubles grid for small-N shapes -> 2 blocks/CU).
// EPI: 0 = bf16 store, 1 = fp32 store + fp32 residual
template <int EPI, int BN>
__global__ __launch_bounds__(256) void k_gemm(const unsigned short* __restrict__ A,
                                              const unsigned short* __restrict__ BT,
                                              int K, int ldc,
                                              unsigned short* Cb,
                                              float* __restrict__ Cf,
                                              const float* __restrict__ Res) {
  constexpr int NW = BN / 32;                 // wave N-subtiles
  __shared__ __align__(16) unsigned short at[128 * 32];
  __shared__ __align__(16) unsigned short bt[BN * 32];
  int t = threadIdx.x, w = t >> 6, l = t & 63;
  int g = l >> 4, c = l & 15;
  int wm = w >> 1, wn = w & 1;
  f32x4 acc[4][NW] = {};
  const unsigned short* gA = A + (size_t)(blockIdx.y * 128 + (t >> 2)) * K + (t & 3) * 8;
  const unsigned short* gB = BT + (size_t)(blockIdx.x * BN + (t >> 2)) * K + (t & 3) * 8;
  unsigned short* dA = &at[w * 512];  // wave-uniform base; HW adds lane*16B
  unsigned short* dB = &bt[w * 512];
  const int nk = K >> 5;
  for (int kt = 0; kt < nk; ++kt) {
    async16(dA, gA);
    async16(dA + 2048, gA + (size_t)64 * K);
    async16(dB, gB);
    if (BN == 128) async16(dB + 2048, gB + (size_t)64 * K);
    gA += 32; gB += 32;
    __syncthreads();
    s16x8 af[4], bfr[NW];
#pragma unroll
    for (int m = 0; m < 4; ++m) af[m] = *(const s16x8*)&at[(wm * 64 + m * 16 + c) * 32 + g * 8];
#pragma unroll
    for (int n = 0; n < NW; ++n)
      bfr[n] = *(const s16x8*)&bt[(wn * (BN / 2) + n * 16 + c) * 32 + g * 8];
#pragma unroll
    for (int m = 0; m < 4; ++m)
#pragma unroll
      for (int n = 0; n < NW; ++n)
        acc[m][n] = mfma_bf16(af[m], bfr[n], acc[m][n]);
    __syncthreads();
  }
  size_t rb = (size_t)blockIdx.y * 128 + wm * 64;
  size_t cbase = (size_t)blockIdx.x * BN + wn * (BN / 2);
#pragma unroll
  for (int m = 0; m < 4; ++m)
#pragma unroll
    for (int n = 0; n < NW; ++n)
#pragma unroll
      for (int r = 0; r < 4; ++r) {
        size_t row = rb + m * 16 + g * 4 + r;      // C row = (lane>>4)*4+reg
        size_t col = cbase + n * 16 + c;           // C col = lane&15
        float v = acc[m][n][r];
        if (EPI == 0) Cb[row * ldc + col] = f2bf(v);
        else Cf[row * ldc + col] = v + Res[row * ldc + col];
      }
}

// ---------- fused gate+up GEMM: inter = silu(A@Wg) * (A@Wu), BM=128 BN=64 ----------
__global__ __launch_bounds__(256) void k_gateup(const unsigned short* __restrict__ A,
                                                const unsigned short* __restrict__ BTg,
                                                const unsigned short* __restrict__ BTu,
                                                unsigned short* __restrict__ Cb) {
  __shared__ __align__(16) unsigned short at[128 * 32];
  __shared__ __align__(16) unsigned short bg[64 * 32];
  __shared__ __align__(16) unsigned short bu[64 * 32];
  int t = threadIdx.x, w = t >> 6, l = t & 63;
  int g = l >> 4, c = l & 15;
  int wm = w >> 1, wn = w & 1;
  f32x4 ag[4][2] = {}, au[4][2] = {};
  const unsigned short* gA = A + (size_t)(blockIdx.y * 128 + (t >> 2)) * 1024 + (t & 3) * 8;
  const unsigned short* gG = BTg + (size_t)(blockIdx.x * 64 + (t >> 2)) * 1024 + (t & 3) * 8;
  const unsigned short* gU = BTu + (size_t)(blockIdx.x * 64 + (t >> 2)) * 1024 + (t & 3) * 8;
  unsigned short* dA = &at[w * 512];
  unsigned short* dG = &bg[w * 512];
  unsigned short* dU = &bu[w * 512];
  for (int kt = 0; kt < 32; ++kt) {
    async16(dA, gA);
    async16(dA + 2048, gA + (size_t)64 * 1024);
    async16(dG, gG);
    async16(dU, gU);
    gA += 32; gG += 32; gU += 32;
    __syncthreads();
    s16x8 af[4], bgf[2], buf_[2];
#pragma unroll
    for (int m = 0; m < 4; ++m) af[m] = *(const s16x8*)&at[(wm * 64 + m * 16 + c) * 32 + g * 8];
#pragma unroll
    for (int n = 0; n < 2; ++n) {
      bgf[n] = *(const s16x8*)&bg[(wn * 32 + n * 16 + c) * 32 + g * 8];
      buf_[n] = *(const s16x8*)&bu[(wn * 32 + n * 16 + c) * 32 + g * 8];
    }
#pragma unroll
    for (int m = 0; m < 4; ++m)
#pragma unroll
      for (int n = 0; n < 2; ++n) {
        ag[m][n] = mfma_bf16(af[m], bgf[n], ag[m][n]);
        au[m][n] = mfma_bf16(af[m], buf_[n], au[m][n]);
      }
    __syncthreads();
  }
  size_t rb = (size_t)blockIdx.y * 128 + wm * 64;
  size_t cb = (size_t)blockIdx.x * 64 + wn * 32;
#pragma unroll
  for (int m = 0; m < 4; ++m)
#pragma unroll
    for (int n = 0; n < 2; ++n)
#pragma unroll
      for (int r = 0; r < 4; ++r) {
        size_t row = rb + m * 16 + g * 4 + r;
        size_t col = cb + n * 16 + c;
        float gv = ag[m][n][r], uv = au[m][n][r];
        Cb[row * 4096 + col] = f2bf(gv / (1.0f + __expf(-gv)) * uv);
      }
}

// ---------- Flash attention: 8 waves, dbuf swizzled tiles, log2 softmax ----------
// l (softmax denominator) computed by the MATRIX pipe: an extra ones-B-fragment MFMA
// accumulates row sums of P alongside O -- removes the 16-lane DPP sum-reduce (VALU).
__global__ __launch_bounds__(512) void k_attn(const unsigned short* __restrict__ Q,
                                              const unsigned short* __restrict__ K,
                                              const unsigned short* __restrict__ VT,
                                              const float* __restrict__ mask,
                                              unsigned short* __restrict__ Out) {
  __shared__ __align__(16) unsigned short Ks[2][64 * 64];
  __shared__ __align__(16) unsigned short VTs[2][64 * 64];
  __shared__ __align__(16) unsigned short Ps[8 * 16 * 68];
  const float LOG2E = 1.44269504f;
  const float SCL2 = 0.125f * 1.44269504f;
  int t = threadIdx.x, w = t >> 6, l = t & 63;
  int g = l >> 4, c = l & 15;
  int qw = w >> 2, hh = w & 3;           // qw 0..1 (16 q-rows), hh 0..3 (head in group)
  int blk = blockIdx.x;
  int qt = blk & 63, kvh = (blk >> 6) & 3, b = blk >> 8;
  size_t tokQ = (size_t)b * SS + qt * 32 + qw * 16;
  int head = kvh * 4 + hh;
  s16x8 qf[2];
#pragma unroll
  for (int st = 0; st < 2; ++st)
    qf[st] = *(const s16x8*)&Q[(tokQ + c) * 1536 + head * 64 + st * 32 + g * 8];
  const s16x8 one8 = {(short)0x3F80, (short)0x3F80, (short)0x3F80, (short)0x3F80,
                      (short)0x3F80, (short)0x3F80, (short)0x3F80, (short)0x3F80};

  // staging: 512 threads, each one 16B slot of K + one of VT
  int srow = t >> 3;
  int soff = srow * 64 + (((t & 7) ^ (srow & 7)) << 3);  // swizzled LDS short-offset
  const unsigned short* gK = K + ((size_t)b * SS + srow) * 1536 + kvh * 64 + (t & 7) * 8;
  const unsigned short* gV = VT + ((size_t)(b * 4 + kvh) * 64 + srow) * SS + (t & 7) * 8;

  int4 rK = *(const int4*)gK;            // tile 0
  int4 rV = *(const int4*)gV;
  *(int4*)&Ks[0][soff] = rK;
  *(int4*)&VTs[0][soff] = rV;

  const float* mrow = mask + (size_t)b * SS * SS + (size_t)(qt * 32 + qw * 16 + g * 4) * SS + c;
  float mcur[4][4], mnxt[4][4];
#pragma unroll
  for (int n = 0; n < 4; ++n)
#pragma unroll
    for (int r = 0; r < 4; ++r) mcur[n][r] = mrow[(size_t)r * SS + n * 16] * LOG2E;

  f32x4 aco[4] = {};
  f32x4 acl = {};                        // softmax denominators (row sums of P)
  float mrun[4];
#pragma unroll
  for (int r = 0; r < 4; ++r) mrun[r] = -1e30f;
  unsigned short* myP = &Ps[w * (16 * 68)];
  __syncthreads();

  for (int kt = 0; kt < 32; ++kt) {
    const unsigned short* Kc = Ks[kt & 1];
    const unsigned short* Vc = VTs[kt & 1];
    int nx = kt < 31 ? kt + 1 : 31;
    // prefetch next K/VT tile + next mask tile into registers
    rK = *(const int4*)(gK + (size_t)nx * 64 * 1536);
    rV = *(const int4*)(gV + nx * 64);
#pragma unroll
    for (int n = 0; n < 4; ++n)
#pragma unroll
      for (int r = 0; r < 4; ++r) mnxt[n][r] = mrow[(size_t)r * SS + nx * 64 + n * 16];

    // S = Q K^T   (rows q = g*4+r, cols k = n*16+c)
    f32x4 as[4] = {};
    __builtin_amdgcn_s_setprio(1);
#pragma unroll
    for (int st = 0; st < 2; ++st)
#pragma unroll
      for (int n = 0; n < 4; ++n) {
        s16x8 kb = *(const s16x8*)&Kc[(n * 16 + c) * 64 + (((st * 4 + g) ^ (c & 7)) << 3)];
        as[n] = mfma_bf16(qf[st], kb, as[n]);
      }
    __builtin_amdgcn_s_setprio(0);
    float sv[4][4];
#pragma unroll
    for (int n = 0; n < 4; ++n)
#pragma unroll
      for (int r = 0; r < 4; ++r) sv[n][r] = as[n][r] * SCL2 + mcur[n][r];
    // row max via DPP (row q = g*4+r lives in the aligned 16-lane group)
    float mx[4];
#pragma unroll
    for (int r = 0; r < 4; ++r) {
      float m0 = fmaxf(fmaxf(sv[0][r], sv[1][r]), fmaxf(sv[2][r], sv[3][r]));
      mx[r] = red16max(m0);
    }
    // defer-max: rescale only when some row's max grew past the 2^8 headroom
    float need = fmaxf(fmaxf(mx[0] - mrun[0], mx[1] - mrun[1]),
                       fmaxf(mx[2] - mrun[2], mx[3] - mrun[3]));
    if (__any(need > 8.0f)) {
#pragma unroll
      for (int r = 0; r < 4; ++r) {
        float mnew = fmaxf(mrun[r], mx[r]);
        float alpha = fexp2(mrun[r] - mnew);
        acl[r] *= alpha;
#pragma unroll
        for (int n = 0; n < 4; ++n) aco[n][r] *= alpha;
        mrun[r] = mnew;
      }
    }
#pragma unroll
    for (int r = 0; r < 4; ++r)
#pragma unroll
      for (int n = 0; n < 4; ++n)
        myP[(g * 4 + r) * 68 + n * 16 + c] = cvt1(fexp2(sv[n][r] - mrun[r]));
    asm volatile("s_waitcnt lgkmcnt(0)" ::: "memory");  // P writes landed (wave-private slab)
    __builtin_amdgcn_sched_barrier(0);                  // rule #18: keep MFMA below the wait
    __builtin_amdgcn_s_setprio(1);
#pragma unroll
    for (int st = 0; st < 2; ++st) {
      s16x8 pa = *(const s16x8*)&myP[c * 68 + st * 32 + g * 8];
#pragma unroll
      for (int n = 0; n < 4; ++n) {
        s16x8 vb = *(const s16x8*)&Vc[(n * 16 + c) * 64 + (((st * 4 + g) ^ (c & 7)) << 3)];
        aco[n] = mfma_bf16(pa, vb, aco[n]);
      }
      acl = mfma_bf16(pa, one8, acl);    // denominator: row sums via matrix pipe
    }
    __builtin_amdgcn_s_setprio(0);
    if (kt < 31) {                       // write prefetched tile kt+1 to the other buffer
      *(int4*)&Ks[(kt + 1) & 1][soff] = rK;
      *(int4*)&VTs[(kt + 1) & 1][soff] = rV;
    }
#pragma unroll
    for (int n = 0; n < 4; ++n)
#pragma unroll
      for (int r = 0; r < 4; ++r) mcur[n][r] = mnxt[n][r] * LOG2E;
    __syncthreads();                     // single barrier per kt (dbuf)
  }
#pragma unroll
  for (int n = 0; n < 4; ++n)
#pragma unroll
    for (int r = 0; r < 4; ++r) {
      float v = aco[n][r] / acl[r];
      Out[(tokQ + g * 4 + r) * 1024 + head * 64 + n * 16 + c] = f2bf(v);
    }
}

extern "C" void kernel_launch(void* const* d_in, const int* in_sizes, int n_in,
                              void* d_out, int out_size, void* d_ws, size_t ws_size,
                              hipStream_t stream) {
  (void)in_sizes; (void)n_in; (void)out_size; (void)ws_size;
  const float* hidden = (const float*)d_in[0];
  const float* kvst   = (const float*)d_in[1];
  const float* maskp  = (const float*)d_in[2];
  const float* ln1    = (const float*)d_in[3];
  const float* ln2    = (const float*)d_in[4];
  const float* Wq     = (const float*)d_in[5];
  const float* Wk     = (const float*)d_in[6];
  const float* Wv     = (const float*)d_in[7];
  const float* Wo     = (const float*)d_in[8];
  const float* Wg     = (const float*)d_in[9];
  const float* Wu     = (const float*)d_in[10];
  const float* Wd     = (const float*)d_in[11];
  float* out = (float*)d_out;

  char* ws = (char*)d_ws;
  size_t off = 0;
  auto alloc = [&](size_t bytes) { char* p = ws + off; off += (bytes + 255) & ~(size_t)255; return p; };
  unsigned short* WTqkv = (unsigned short*)alloc((size_t)1536 * 1024 * 2);
  unsigned short* WTo   = (unsigned short*)alloc((size_t)1024 * 1024 * 2);
  unsigned short* WTg   = (unsigned short*)alloc((size_t)4096 * 1024 * 2);
  unsigned short* WTu   = (unsigned short*)alloc((size_t)4096 * 1024 * 2);
  unsigned short* WTd   = (unsigned short*)alloc((size_t)1024 * 4096 * 2);
  float* cosT           = (float*)alloc((size_t)2048 * 32 * 4);
  float* sinT           = (float*)alloc((size_t)2048 * 32 * 4);
  unsigned short* hn    = (unsigned short*)alloc((size_t)4096 * 1024 * 2);
  unsigned short* kvn   = (unsigned short*)alloc((size_t)4096 * 1024 * 2);
  unsigned short* QKVb  = (unsigned short*)alloc((size_t)4096 * 1536 * 2);
  unsigned short* VTg   = (unsigned short*)alloc((size_t)8 * 64 * SS * 2);
  float* hid2           = (float*)alloc((size_t)4096 * 1024 * 4);
  unsigned short* inter = (unsigned short*)alloc((size_t)4096 * 4096 * 2);
  unsigned short* attnb = hn;              // hn dead after Q-proj
  unsigned short* h2n   = kvn;             // kvn dead after KV-proj

  // weights -> bf16 transposed (QKV packed: rows 0..1023 = Wq, 1024..1279 = Wk, 1280..1535 = Wv)
  k_transpose<<<dim3(32, 32), 256, 0, stream>>>(Wq, WTqkv, 1024, 1024);
  k_transpose<<<dim3(8, 32), 256, 0, stream>>>(Wk, WTqkv + (size_t)1024 * 1024, 1024, 256);
  k_transpose<<<dim3(8, 32), 256, 0, stream>>>(Wv, WTqkv + (size_t)1280 * 1024, 1024, 256);
  k_transpose<<<dim3(32, 32), 256, 0, stream>>>(Wo, WTo, 1024, 1024);
  k_transpose<<<dim3(128, 32), 256, 0, stream>>>(Wg, WTg, 1024, 4096);
  k_transpose<<<dim3(128, 32), 256, 0, stream>>>(Wu, WTu, 1024, 4096);
  k_transpose<<<dim3(32, 128), 256, 0, stream>>>(Wd, WTd, 4096, 1024);
  k_rope_tables<<<256, 256, 0, stream>>>(cosT, sinT);
  // norms
  k_rmsnorm<<<4096, 256, 0, stream>>>(hidden, ln1, hn);
  k_rmsnorm<<<4096, 256, 0, stream>>>(kvst, ln1, kvn);
  // projections into packed QKV [4096][1536]  (BN=64 -> 2 blocks/CU)
  k_gemm<0, 64><<<dim3(16, 32), 256, 0, stream>>>(hn, WTqkv, 1024, 1536, QKVb, nullptr, nullptr);
  k_gemm<0, 64><<<dim3(8, 32), 256, 0, stream>>>(kvn, WTqkv + (size_t)1024 * 1024, 1024, 1536,
                                                 QKVb + 1024, nullptr, nullptr);
  // rope: heads 0..15 = Q, 16..19 = K (col h*64 in packed layout); V untouched
  k_rope<<<dim3(128, 20), 256, 0, stream>>>(QKVb, cosT, sinT, 1536);
  // V^T for conflict-free attention staging
  k_vtrans<<<dim3(64, 2, 8), 256, 0, stream>>>(QKVb, VTg);
  // attention
  k_attn<<<512, 512, 0, stream>>>(QKVb, QKVb + 1024, VTg, maskp, attnb);
  // O proj + residual
  k_gemm<1, 64><<<dim3(16, 32), 256, 0, stream>>>(attnb, WTo, 1024, 1024, nullptr, hid2, hidden);
  // MLP
  k_rmsnorm<<<4096, 256, 0, stream>>>(hid2, ln2, h2n);
  k_gateup<<<dim3(64, 32), 256, 0, stream>>>(h2n, WTg, WTu, inter);
  k_gemm<1, 64><<<dim3(16, 32), 256, 0, stream>>>(inter, WTd, 4096, 1024, nullptr, out, hid2);
}

// Round 8
// 345.879 us; speedup vs baseline: 1.4409x; 1.0410x over previous
//
#include <hip/hip_runtime.h>
#include <math.h>

#define SS 2048

typedef __attribute__((ext_vector_type(8))) short s16x8;
typedef __attribute__((ext_vector_type(4))) float f32x4;
typedef __attribute__((ext_vector_type(16))) float f32x16;

__device__ __forceinline__ unsigned short f2bf(float f) {
  union { float f; unsigned u; } a; a.f = f;
  unsigned r = a.u + 0x7fffu + ((a.u >> 16) & 1u);   // RNE
  return (unsigned short)(r >> 16);
}
__device__ __forceinline__ float bf2f(unsigned short b) {
  union { unsigned u; float f; } a; a.u = ((unsigned)b) << 16;
  return a.f;
}
// packed f32->bf16 (RNE): dword = {lo: bf16(a), hi: bf16(b)}
__device__ __forceinline__ unsigned cvtpk(float a, float b) {
  unsigned d; asm("v_cvt_pk_bf16_f32 %0, %1, %2" : "=v"(d) : "v"(a), "v"(b)); return d;
}
// raw v_exp_f32 = 2^x
__device__ __forceinline__ float fexp2(float x) {
  float r; asm("v_exp_f32 %0, %1" : "=v"(r) : "v"(x)); return r;
}
__device__ __forceinline__ void async16(void* lds, const void* g) {
  __builtin_amdgcn_global_load_lds(
      (const __attribute__((address_space(1))) unsigned int*)g,
      (__attribute__((address_space(3))) unsigned int*)lds, 16, 0, 0);
}
__device__ __forceinline__ f32x4 mfma_bf16(s16x8 a, s16x8 b, f32x4 c) {
  return __builtin_amdgcn_mfma_f32_16x16x32_bf16(a, b, c, 0, 0, 0);
}
__device__ __forceinline__ f32x16 mfma32(s16x8 a, s16x8 b, f32x16 c) {
  return __builtin_amdgcn_mfma_f32_32x32x16_bf16(a, b, c, 0, 0, 0);
}

// ---------- transpose + fp32->bf16: WT[n][k] = bf16(W[k][n]) ----------
__global__ __launch_bounds__(256) void k_transpose(const float* __restrict__ W,
                                                   unsigned short* __restrict__ WT,
                                                   int K, int N) {
  __shared__ float tile[32][33];
  int t = threadIdx.x;
  int tx = t & 31, ty = t >> 5;
  int n0 = blockIdx.x * 32, k0 = blockIdx.y * 32;
#pragma unroll
  for (int i = 0; i < 4; ++i)
    tile[ty + 8 * i][tx] = W[(size_t)(k0 + ty + 8 * i) * N + n0 + tx];
  __syncthreads();
#pragma unroll
  for (int i = 0; i < 4; ++i)
    WT[(size_t)(n0 + ty + 8 * i) * K + k0 + tx] = f2bf(tile[tx][ty + 8 * i]);
}

// ---------- V^T precompute: VT[(b*4+kvh)][d=64][s=2048] from QKV cols 1280.. ----------
__global__ __launch_bounds__(256) void k_vtrans(const unsigned short* __restrict__ QKV,
                                                unsigned short* __restrict__ VT) {
  __shared__ unsigned short tile[32][33];
  int t = threadIdx.x, tx = t & 31, ty = t >> 5;
  int s0 = blockIdx.x * 32, d0 = blockIdx.y * 32;
  int bk = blockIdx.z; int b = bk >> 2, kvh = bk & 3;
#pragma unroll
  for (int i = 0; i < 4; ++i)
    tile[ty + 8 * i][tx] =
        QKV[((size_t)b * SS + s0 + ty + 8 * i) * 1536 + 1280 + kvh * 64 + d0 + tx];
  __syncthreads();
#pragma unroll
  for (int i = 0; i < 4; ++i)
    VT[((size_t)bk * 64 + d0 + ty + 8 * i) * SS + s0 + tx] = tile[tx][ty + 8 * i];
}

// ---------- RoPE tables (double precision, once per launch) ----------
__global__ void k_rope_tables(float* __restrict__ cosT, float* __restrict__ sinT) {
  int idx = blockIdx.x * 256 + threadIdx.x;  // 65536 = 2048*32
  int s = idx >> 5, i = idx & 31;
  double ang = (double)s * pow(10000.0, -(double)(2 * i) / 64.0);
  cosT[idx] = (float)cos(ang);
  sinT[idx] = (float)sin(ang);
}

// ---------- RMSNorm fp32 -> bf16 (one block per row, H=1024) ----------
__global__ __launch_bounds__(256) void k_rmsnorm(const float* __restrict__ X,
                                                 const float* __restrict__ Wt,
                                                 unsigned short* __restrict__ Y) {
  int row = blockIdx.x, t = threadIdx.x;
  float4 v = ((const float4*)X)[(size_t)row * 256 + t];
  float ssq = v.x * v.x + v.y * v.y + v.z * v.z + v.w * v.w;
#pragma unroll
  for (int m = 1; m < 64; m <<= 1) ssq += __shfl_xor(ssq, m);
  __shared__ float red[4];
  if ((t & 63) == 0) red[t >> 6] = ssq;
  __syncthreads();
  float sc = rsqrtf((red[0] + red[1] + red[2] + red[3]) * (1.0f / 1024.0f) + 1e-6f);
  float4 wv = ((const float4*)Wt)[t];
  ushort4 o;
  o.x = f2bf(v.x * sc * wv.x); o.y = f2bf(v.y * sc * wv.y);
  o.z = f2bf(v.z * sc * wv.z); o.w = f2bf(v.w * sc * wv.w);
  ((ushort4*)Y)[(size_t)row * 256 + t] = o;
}

// ---------- RoPE in place on QKV buffer; head = blockIdx.y ----------
__global__ __launch_bounds__(256) void k_rope(unsigned short* __restrict__ X,
                                              const float* __restrict__ cosT,
                                              const float* __restrict__ sinT,
                                              int stride) {
  int idx = blockIdx.x * 256 + threadIdx.x;  // tok*8+seg, tok 0..4095
  int seg = idx & 7, tok = idx >> 3;
  int head = blockIdx.y;
  int s = tok & (SS - 1);
  int d0 = seg * 4;
  unsigned short* p = X + (size_t)tok * stride + head * 64;
  ushort4 lo = *(ushort4*)&p[d0];
  ushort4 hi = *(ushort4*)&p[d0 + 32];
  float4 cs = *(const float4*)&cosT[s * 32 + d0];
  float4 sn = *(const float4*)&sinT[s * 32 + d0];
  ushort4 olo, ohi;
  olo.x = f2bf(bf2f(lo.x) * cs.x - bf2f(hi.x) * sn.x);
  olo.y = f2bf(bf2f(lo.y) * cs.y - bf2f(hi.y) * sn.y);
  olo.z = f2bf(bf2f(lo.z) * cs.z - bf2f(hi.z) * sn.z);
  olo.w = f2bf(bf2f(lo.w) * cs.w - bf2f(hi.w) * sn.w);
  ohi.x = f2bf(bf2f(hi.x) * cs.x + bf2f(lo.x) * sn.x);
  ohi.y = f2bf(bf2f(hi.y) * cs.y + bf2f(lo.y) * sn.y);
  ohi.z = f2bf(bf2f(hi.z) * cs.z + bf2f(lo.z) * sn.z);
  ohi.w = f2bf(bf2f(hi.w) * cs.w + bf2f(lo.w) * sn.w);
  *(ushort4*)&p[d0] = olo;
  *(ushort4*)&p[d0 + 32] = ohi;
}

// ---------- GEMM: C[M,N] = A[M,K](bf16) x BT[N,K](bf16), m97 structure ----------
template <int EPI, int BN>
__global__ __launch_bounds__(256) void k_gemm(const unsigned short* __restrict__ A,
                                              const unsigned short* __restrict__ BT,
                                              int K, int ldc,
                                              unsigned short* Cb,
                                              float* __restrict__ Cf,
                                              const float* __restrict__ Res) {
  constexpr int NW = BN / 32;
  __shared__ __align__(16) unsigned short at[128 * 32];
  __shared__ __align__(16) unsigned short bt[BN * 32];
  int t = threadIdx.x, w = t >> 6, l = t & 63;
  int g = l >> 4, c = l & 15;
  int wm = w >> 1, wn = w & 1;
  f32x4 acc[4][NW] = {};
  const unsigned short* gA = A + (size_t)(blockIdx.y * 128 + (t >> 2)) * K + (t & 3) * 8;
  const unsigned short* gB = BT + (size_t)(blockIdx.x * BN + (t >> 2)) * K + (t & 3) * 8;
  unsigned short* dA = &at[w * 512];
  unsigned short* dB = &bt[w * 512];
  const int nk = K >> 5;
  for (int kt = 0; kt < nk; ++kt) {
    async16(dA, gA);
    async16(dA + 2048, gA + (size_t)64 * K);
    async16(dB, gB);
    if (BN == 128) async16(dB + 2048, gB + (size_t)64 * K);
    gA += 32; gB += 32;
    __syncthreads();
    s16x8 af[4], bfr[NW];
#pragma unroll
    for (int m = 0; m < 4; ++m) af[m] = *(const s16x8*)&at[(wm * 64 + m * 16 + c) * 32 + g * 8];
#pragma unroll
    for (int n = 0; n < NW; ++n)
      bfr[n] = *(const s16x8*)&bt[(wn * (BN / 2) + n * 16 + c) * 32 + g * 8];
#pragma unroll
    for (int m = 0; m < 4; ++m)
#pragma unroll
      for (int n = 0; n < NW; ++n)
        acc[m][n] = mfma_bf16(af[m], bfr[n], acc[m][n]);
    __syncthreads();
  }
  size_t rb = (size_t)blockIdx.y * 128 + wm * 64;
  size_t cbase = (size_t)blockIdx.x * BN + wn * (BN / 2);
#pragma unroll
  for (int m = 0; m < 4; ++m)
#pragma unroll
    for (int n = 0; n < NW; ++n)
#pragma unroll
      for (int r = 0; r < 4; ++r) {
        size_t row = rb + m * 16 + g * 4 + r;
        size_t col = cbase + n * 16 + c;
        float v = acc[m][n][r];
        if (EPI == 0) Cb[row * ldc + col] = f2bf(v);
        else Cf[row * ldc + col] = v + Res[row * ldc + col];
      }
}

// ---------- fused gate+up GEMM: inter = silu(A@Wg) * (A@Wu), BM=128 BN=64 ----------
__global__ __launch_bounds__(256) void k_gateup(const unsigned short* __restrict__ A,
                                                const unsigned short* __restrict__ BTg,
                                                const unsigned short* __restrict__ BTu,
                                                unsigned short* __restrict__ Cb) {
  __shared__ __align__(16) unsigned short at[128 * 32];
  __shared__ __align__(16) unsigned short bg[64 * 32];
  __shared__ __align__(16) unsigned short bu[64 * 32];
  int t = threadIdx.x, w = t >> 6, l = t & 63;
  int g = l >> 4, c = l & 15;
  int wm = w >> 1, wn = w & 1;
  f32x4 ag[4][2] = {}, au[4][2] = {};
  const unsigned short* gA = A + (size_t)(blockIdx.y * 128 + (t >> 2)) * 1024 + (t & 3) * 8;
  const unsigned short* gG = BTg + (size_t)(blockIdx.x * 64 + (t >> 2)) * 1024 + (t & 3) * 8;
  const unsigned short* gU = BTu + (size_t)(blockIdx.x * 64 + (t >> 2)) * 1024 + (t & 3) * 8;
  unsigned short* dA = &at[w * 512];
  unsigned short* dG = &bg[w * 512];
  unsigned short* dU = &bu[w * 512];
  for (int kt = 0; kt < 32; ++kt) {
    async16(dA, gA);
    async16(dA + 2048, gA + (size_t)64 * 1024);
    async16(dG, gG);
    async16(dU, gU);
    gA += 32; gG += 32; gU += 32;
    __syncthreads();
    s16x8 af[4], bgf[2], buf_[2];
#pragma unroll
    for (int m = 0; m < 4; ++m) af[m] = *(const s16x8*)&at[(wm * 64 + m * 16 + c) * 32 + g * 8];
#pragma unroll
    for (int n = 0; n < 2; ++n) {
      bgf[n] = *(const s16x8*)&bg[(wn * 32 + n * 16 + c) * 32 + g * 8];
      buf_[n] = *(const s16x8*)&bu[(wn * 32 + n * 16 + c) * 32 + g * 8];
    }
#pragma unroll
    for (int m = 0; m < 4; ++m)
#pragma unroll
      for (int n = 0; n < 2; ++n) {
        ag[m][n] = mfma_bf16(af[m], bgf[n], ag[m][n]);
        au[m][n] = mfma_bf16(af[m], buf_[n], au[m][n]);
      }
    __syncthreads();
  }
  size_t rb = (size_t)blockIdx.y * 128 + wm * 64;
  size_t cb = (size_t)blockIdx.x * 64 + wn * 32;
#pragma unroll
  for (int m = 0; m < 4; ++m)
#pragma unroll
    for (int n = 0; n < 2; ++n)
#pragma unroll
      for (int r = 0; r < 4; ++r) {
        size_t row = rb + m * 16 + g * 4 + r;
        size_t col = cb + n * 16 + c;
        float gv = ag[m][n][r], uv = au[m][n][r];
        Cb[row * 4096 + col] = f2bf(gv / (1.0f + __expf(-gv)) * uv);
      }
}

// ---------- Flash attention, 32x32 swapped QK^T, in-register softmax ----------
// Block = 256 thr = 4 waves = the 4 Q-heads of one GQA group; 32 q-rows per block.
// S^T = mfma32(K,Q): lane owns q = lane&31, holds 32 k-scores in regs.
// P rebuilt in-register via cvt_pk + shfl_xor(32) into PV A-fragments (no P LDS).
// Denominator acl via ones-MFMA; rows of acc follow crow(r,hi)=(r&3)+8*(r>>2)+4*hi.
__global__ __launch_bounds__(256) void k_attn(const unsigned short* __restrict__ Q,
                                              const unsigned short* __restrict__ K,
                                              const unsigned short* __restrict__ VT,
                                              const float* __restrict__ mask,
                                              unsigned short* __restrict__ Out) {
  __shared__ __align__(16) unsigned short Ks[2][64 * 64];
  __shared__ __align__(16) unsigned short VTs[2][64 * 64];
  const float LOG2E = 1.44269504f;
  int t = threadIdx.x, w = t >> 6, l = t & 63;
  int q32 = l & 31, hi = l >> 5;
  int blk = blockIdx.x;
  int qt = blk & 63, kvh = (blk >> 6) & 3, b = blk >> 8;
  int head = kvh * 4 + w;
  size_t tokQ = (size_t)b * SS + qt * 32;

  s16x8 qfr[4];   // Q[tokQ+q32][head*64 + d*16 + hi*8 + 0..7]
#pragma unroll
  for (int d = 0; d < 4; ++d)
    qfr[d] = *(const s16x8*)&Q[(tokQ + q32) * 1536 + head * 64 + d * 16 + hi * 8];
  const s16x8 one8 = {(short)0x3F80, (short)0x3F80, (short)0x3F80, (short)0x3F80,
                      (short)0x3F80, (short)0x3F80, (short)0x3F80, (short)0x3F80};

  // staging: 256 threads x 2 slots each for K and VT (16B slots, XOR-swizzled)
  int id0 = t, id1 = t + 256;
  int row0 = id0 >> 3, b80 = id0 & 7;
  int row1 = id1 >> 3, b81 = id1 & 7;
  int so0 = row0 * 64 + ((b80 ^ (row0 & 7)) << 3);
  int so1 = row1 * 64 + ((b81 ^ (row1 & 7)) << 3);
  const unsigned short* gK = K + (size_t)b * SS * 1536 + kvh * 64;
  const unsigned short* gV = VT + (size_t)(b * 4 + kvh) * 64 * SS;

  int4 rK0 = *(const int4*)(gK + (size_t)row0 * 1536 + b80 * 8);
  int4 rK1 = *(const int4*)(gK + (size_t)row1 * 1536 + b81 * 8);
  int4 rV0 = *(const int4*)(gV + (size_t)row0 * SS + b80 * 8);
  int4 rV1 = *(const int4*)(gV + (size_t)row1 * SS + b81 * 8);
  *(int4*)&Ks[0][so0] = rK0; *(int4*)&Ks[0][so1] = rK1;
  *(int4*)&VTs[0][so0] = rV0; *(int4*)&VTs[0][so1] = rV1;

  // mask base for this lane's q-row; +4*hi folds the hi-offset of crow
  const float* mrowp = mask + (size_t)b * SS * SS + (size_t)(qt * 32 + q32) * SS + 4 * hi;
  float mc0[16], mc1[16];
#pragma unroll
  for (int r = 0; r < 16; ++r) {
    mc0[r] = mrowp[(r & 3) + 8 * (r >> 2)];
    mc1[r] = mrowp[32 + (r & 3) + 8 * (r >> 2)];
  }

  f32x16 aco0 = {}, aco1 = {}, acl = {};
  float mrun = -1e30f;
  __syncthreads();

  for (int kt = 0; kt < 32; ++kt) {
    const unsigned short* Kc = Ks[kt & 1];
    const unsigned short* Vc = VTs[kt & 1];
    if (kt < 31) {   // prefetch next tile into regs (written after the barrier region)
      int kb = (kt + 1) * 64;
      rK0 = *(const int4*)(gK + (size_t)(kb + row0) * 1536 + b80 * 8);
      rK1 = *(const int4*)(gK + (size_t)(kb + row1) * 1536 + b81 * 8);
      rV0 = *(const int4*)(gV + (size_t)row0 * SS + kb + b80 * 8);
      rV1 = *(const int4*)(gV + (size_t)row1 * SS + kb + b81 * 8);
    }
    // S^T = K . Q^T  (rows k, cols q=lane&31); two 32-k subtiles
    f32x16 s0 = {}, s1 = {};
    __builtin_amdgcn_s_setprio(1);
#pragma unroll
    for (int d = 0; d < 4; ++d) {
      s16x8 ka = *(const s16x8*)&Kc[q32 * 64 + (((d * 2 + hi) ^ (q32 & 7)) << 3)];
      s0 = mfma32(ka, qfr[d], s0);
      int r2 = 32 + q32;
      s16x8 kb2 = *(const s16x8*)&Kc[r2 * 64 + (((d * 2 + hi) ^ (r2 & 7)) << 3)];
      s1 = mfma32(kb2, qfr[d], s1);
    }
    __builtin_amdgcn_s_setprio(0);
    // log2-domain scores
    float sv0[16], sv1[16];
#pragma unroll
    for (int r = 0; r < 16; ++r) {
      sv0[r] = (s0[r] * 0.125f + mc0[r]) * LOG2E;
      sv1[r] = (s1[r] * 0.125f + mc1[r]) * LOG2E;
    }
    // issue next tile's mask loads now (consumed next iter; latency hidden)
    {
      int nk = (kt < 31 ? kt + 1 : 31) * 64;
#pragma unroll
      for (int r = 0; r < 16; ++r) {
        mc0[r] = mrowp[nk + (r & 3) + 8 * (r >> 2)];
        mc1[r] = mrowp[nk + 32 + (r & 3) + 8 * (r >> 2)];
      }
    }
    // row max (lane-local q): reg tree + cross-half combine
    float mx = sv0[0];
#pragma unroll
    for (int r = 1; r < 16; ++r) mx = fmaxf(mx, sv0[r]);
#pragma unroll
    for (int r = 0; r < 16; ++r) mx = fmaxf(mx, sv1[r]);
    mx = fmaxf(mx, __shfl_xor(mx, 32));
    // defer-max rescale (rare); alpha redistributed to accumulator rows via shfl
    if (__any(mx > mrun + 8.0f)) {
      float mnew = fmaxf(mrun, mx);
      float alpha = fexp2(mrun - mnew);
      mrun = mnew;
#pragma unroll
      for (int r = 0; r < 16; ++r) {
        float al = __shfl(alpha, (r & 3) + 8 * (r >> 2) + 4 * hi);
        aco0[r] *= al; aco1[r] *= al; acl[r] *= al;
      }
    }
    // P = 2^(sv - mrun) -> bf16 pack -> cross-half exchange -> PV A-frags
    s16x8 pa[4];
#pragma unroll
    for (int ks = 0; ks < 2; ++ks) {
      float p[16];
      if (ks == 0) {
#pragma unroll
        for (int r = 0; r < 16; ++r) p[r] = fexp2(sv0[r] - mrun);
      } else {
#pragma unroll
        for (int r = 0; r < 16; ++r) p[r] = fexp2(sv1[r] - mrun);
      }
      unsigned w8[8];
#pragma unroll
      for (int i = 0; i < 8; ++i) w8[i] = cvtpk(p[2 * i], p[2 * i + 1]);
      unsigned sd0 = hi ? w8[0] : w8[2];
      unsigned sd1 = hi ? w8[1] : w8[3];
      unsigned sd2 = hi ? w8[4] : w8[6];
      unsigned sd3 = hi ? w8[5] : w8[7];
      unsigned rc0 = (unsigned)__shfl_xor((int)sd0, 32);
      unsigned rc1 = (unsigned)__shfl_xor((int)sd1, 32);
      unsigned rc2 = (unsigned)__shfl_xor((int)sd2, 32);
      unsigned rc3 = (unsigned)__shfl_xor((int)sd3, 32);
      union { int4 i; s16x8 v; } fa, fb;
      fa.i.x = hi ? rc0 : w8[0]; fa.i.y = hi ? rc1 : w8[1];
      fa.i.z = hi ? w8[2] : rc0; fa.i.w = hi ? w8[3] : rc1;
      fb.i.x = hi ? rc2 : w8[4]; fb.i.y = hi ? rc3 : w8[5];
      fb.i.z = hi ? w8[6] : rc2; fb.i.w = hi ? w8[7] : rc3;
      pa[2 * ks] = fa.v;
      pa[2 * ks + 1] = fb.v;
    }
    // PV + denominator on matrix pipe
    __builtin_amdgcn_s_setprio(1);
#pragma unroll
    for (int ks = 0; ks < 4; ++ks) {
      s16x8 va = *(const s16x8*)&Vc[q32 * 64 + (((ks * 2 + hi) ^ (q32 & 7)) << 3)];
      aco0 = mfma32(pa[ks], va, aco0);
      int r2 = 32 + q32;
      s16x8 vb2 = *(const s16x8*)&Vc[r2 * 64 + (((ks * 2 + hi) ^ (r2 & 7)) << 3)];
      aco1 = mfma32(pa[ks], vb2, aco1);
      acl = mfma32(pa[ks], one8, acl);
    }
    __builtin_amdgcn_s_setprio(0);
    if (kt < 31) {   // publish prefetched tile kt+1
      int nb = (kt + 1) & 1;
      *(int4*)&Ks[nb][so0] = rK0; *(int4*)&Ks[nb][so1] = rK1;
      *(int4*)&VTs[nb][so0] = rV0; *(int4*)&VTs[nb][so1] = rV1;
    }
    __syncthreads();   // single barrier per kt
  }
  // epilogue: rows follow crow(r,hi); cols = lane&31 (+dtile*32)
#pragma unroll
  for (int r = 0; r < 16; ++r) {
    float inv = 1.0f / acl[r];
    size_t orow = tokQ + (r & 3) + 8 * (r >> 2) + 4 * hi;
    Out[orow * 1024 + head * 64 + q32] = f2bf(aco0[r] * inv);
    Out[orow * 1024 + head * 64 + 32 + q32] = f2bf(aco1[r] * inv);
  }
}

extern "C" void kernel_launch(void* const* d_in, const int* in_sizes, int n_in,
                              void* d_out, int out_size, void* d_ws, size_t ws_size,
                              hipStream_t stream) {
  (void)in_sizes; (void)n_in; (void)out_size; (void)ws_size;
  const float* hidden = (const float*)d_in[0];
  const float* kvst   = (const float*)d_in[1];
  const float* maskp  = (const float*)d_in[2];
  const float* ln1    = (const float*)d_in[3];
  const float* ln2    = (const float*)d_in[4];
  const float* Wq     = (const float*)d_in[5];
  const float* Wk     = (const float*)d_in[6];
  const float* Wv     = (const float*)d_in[7];
  const float* Wo     = (const float*)d_in[8];
  const float* Wg     = (const float*)d_in[9];
  const float* Wu     = (const float*)d_in[10];
  const float* Wd     = (const float*)d_in[11];
  float* out = (float*)d_out;

  char* ws = (char*)d_ws;
  size_t off = 0;
  auto alloc = [&](size_t bytes) { char* p = ws + off; off += (bytes + 255) & ~(size_t)255; return p; };
  unsigned short* WTqkv = (unsigned short*)alloc((size_t)1536 * 1024 * 2);
  unsigned short* WTo   = (unsigned short*)alloc((size_t)1024 * 1024 * 2);
  unsigned short* WTg   = (unsigned short*)alloc((size_t)4096 * 1024 * 2);
  unsigned short* WTu   = (unsigned short*)alloc((size_t)4096 * 1024 * 2);
  unsigned short* WTd   = (unsigned short*)alloc((size_t)1024 * 4096 * 2);
  float* cosT           = (float*)alloc((size_t)2048 * 32 * 4);
  float* sinT           = (float*)alloc((size_t)2048 * 32 * 4);
  unsigned short* hn    = (unsigned short*)alloc((size_t)4096 * 1024 * 2);
  unsigned short* kvn   = (unsigned short*)alloc((size_t)4096 * 1024 * 2);
  unsigned short* QKVb  = (unsigned short*)alloc((size_t)4096 * 1536 * 2);
  unsigned short* VTg   = (unsigned short*)alloc((size_t)8 * 64 * SS * 2);
  float* hid2           = (float*)alloc((size_t)4096 * 1024 * 4);
  unsigned short* inter = (unsigned short*)alloc((size_t)4096 * 4096 * 2);
  unsigned short* attnb = hn;              // hn dead after Q-proj
  unsigned short* h2n   = kvn;             // kvn dead after KV-proj

  // weights -> bf16 transposed (QKV packed: rows 0..1023 = Wq, 1024..1279 = Wk, 1280..1535 = Wv)
  k_transpose<<<dim3(32, 32), 256, 0, stream>>>(Wq, WTqkv, 1024, 1024);
  k_transpose<<<dim3(8, 32), 256, 0, stream>>>(Wk, WTqkv + (size_t)1024 * 1024, 1024, 256);
  k_transpose<<<dim3(8, 32), 256, 0, stream>>>(Wv, WTqkv + (size_t)1280 * 1024, 1024, 256);
  k_transpose<<<dim3(32, 32), 256, 0, stream>>>(Wo, WTo, 1024, 1024);
  k_transpose<<<dim3(128, 32), 256, 0, stream>>>(Wg, WTg, 1024, 4096);
  k_transpose<<<dim3(128, 32), 256, 0, stream>>>(Wu, WTu, 1024, 4096);
  k_transpose<<<dim3(32, 128), 256, 0, stream>>>(Wd, WTd, 4096, 1024);
  k_rope_tables<<<256, 256, 0, stream>>>(cosT, sinT);
  // norms
  k_rmsnorm<<<4096, 256, 0, stream>>>(hidden, ln1, hn);
  k_rmsnorm<<<4096, 256, 0, stream>>>(kvst, ln1, kvn);
  // projections into packed QKV [4096][1536]  (BN=64 -> 2 blocks/CU)
  k_gemm<0, 64><<<dim3(16, 32), 256, 0, stream>>>(hn, WTqkv, 1024, 1536, QKVb, nullptr, nullptr);
  k_gemm<0, 64><<<dim3(8, 32), 256, 0, stream>>>(kvn, WTqkv + (size_t)1024 * 1024, 1024, 1536,
                                                 QKVb + 1024, nullptr, nullptr);
  // rope: heads 0..15 = Q, 16..19 = K (col h*64 in packed layout); V untouched
  k_rope<<<dim3(128, 20), 256, 0, stream>>>(QKVb, cosT, sinT, 1536);
  // V^T for conflict-free attention staging
  k_vtrans<<<dim3(64, 2, 8), 256, 0, stream>>>(QKVb, VTg);
  // attention (4-wave blocks, 2/CU)
  k_attn<<<512, 256, 0, stream>>>(QKVb, QKVb + 1024, VTg, maskp, attnb);
  // O proj + residual
  k_gemm<1, 64><<<dim3(16, 32), 256, 0, stream>>>(attnb, WTo, 1024, 1024, nullptr, hid2, hidden);
  // MLP
  k_rmsnorm<<<4096, 256, 0, stream>>>(hid2, ln2, h2n);
  k_gateup<<<dim3(64, 32), 256, 0, stream>>>(h2n, WTg, WTu, inter);
  k_gemm<1, 64><<<dim3(16, 32), 256, 0, stream>>>(inter, WTd, 4096, 1024, nullptr, out, hid2);
}